// Round 6
// baseline (709.302 us; speedup 1.0000x reference)
//
#include <hip/hip_runtime.h>

#define T_SEQ 256
#define PH  72
#define HSZ 1152

typedef __bf16 bf16x8 __attribute__((ext_vector_type(8)));
typedef float f32x4 __attribute__((ext_vector_type(4)));
typedef _Float16 f16x8 __attribute__((ext_vector_type(8)));

__device__ __forceinline__ float b2f(unsigned short u) {
    union { unsigned int i; float f; } v; v.i = ((unsigned int)u) << 16; return v.f;
}
__device__ __forceinline__ unsigned short f2b(float f) {
    unsigned int x = __builtin_bit_cast(unsigned int, f);
    unsigned int r = (x + 0x7fffu + ((x >> 16) & 1u)) >> 16;
    return (unsigned short)r;
}
__device__ __forceinline__ float sigmoid_f(float x) {
    float e = __builtin_amdgcn_exp2f(-1.4426950408889634f * x);
    return __builtin_amdgcn_rcpf(1.0f + e);
}
__device__ __forceinline__ float tanh_f(float x) {
    float e = __builtin_amdgcn_exp2f(-2.8853900817779268f * x);
    return 2.0f * __builtin_amdgcn_rcpf(1.0f + e) - 1.0f;
}
// fp32 weight row -> hi/lo bf16 fragments (8 along k)
__device__ __forceinline__ void load_frag32(const float* wp, int n, int K, int k0,
                                            bf16x8& hi, bf16x8& lo) {
    const float* wf = wp + (size_t)n * K + k0;
    #pragma unroll
    for (int j = 0; j < 8; ++j) {
        const float v = wf[j];
        const unsigned short h = f2b(v);
        hi[j] = __builtin_bit_cast(__bf16, h);
        lo[j] = __builtin_bit_cast(__bf16, f2b(v - b2f(h)));
    }
}
// async global->LDS, 16 B per lane; lds dest must be wave-uniform (HW adds lane*16)
__device__ __forceinline__ void gload16(const void* g, void* l) {
    __builtin_amdgcn_global_load_lds(
        (const __attribute__((address_space(1))) unsigned int*)g,
        (__attribute__((address_space(3))) unsigned int*)l, 16, 0, 0);
}

#define MFMA(a, b, c) __builtin_amdgcn_mfma_f32_16x16x32_bf16(a, b, c, 0, 0, 0)

// ================= proj0: xp[bb][t][tid][16] fp16, bias folded =================
// lane tid computes (g=0..3, r=0..3) for batch row quad*4+r, gate g*64+w*16+l16 —
// exactly what rec's identical tid consumes at step t. 2x16B stores per t.
#define XT   136    // per-t LDS stride (elems)
#define XROW 1096   // per-row LDS stride (8*136 + 8 pad)
__global__ __launch_bounds__(256) void proj0_kernel(
    const float* __restrict__ x, const float* __restrict__ wih0,
    const float* __restrict__ bih0, const float* __restrict__ bhh0,
    _Float16* __restrict__ xp)
{
    __shared__ unsigned short xh[16 * XROW];
    __shared__ unsigned short xl[16 * XROW];
    const int bb = blockIdx.x >> 2;
    const int tt = (blockIdx.x & 3) * 64;
    const int tid = threadIdx.x, lane = tid & 63, w = tid >> 6;
    const int l16 = lane & 15, quad = lane >> 4, k0 = quad * 8;

    bf16x8 fwh[4][4], fwl[4][4];
    float gb[4];
    #pragma unroll
    for (int g = 0; g < 4; ++g) {
        const int n = g * 64 + w * 16 + l16;
        #pragma unroll
        for (int ks = 0; ks < 4; ++ks)
            load_frag32(wih0, n, 128, ks * 32 + k0, fwh[g][ks], fwl[g][ks]);
        gb[g] = bih0[n] + bhh0[n];
    }

    for (int win = 0; win < 8; ++win) {          // 8 timesteps per window
        __syncthreads();
        #pragma unroll
        for (int it = 0; it < 16; ++it) {        // stage 16 rows x 128 d x 8 t, hi/lo
            const int e = it * 256 + tid;        // e = row*256 + d*2 + t4
            const int t4 = e & 1, d = (e >> 1) & 127, row = e >> 8;
            const float4 v = *(const float4*)(x +
                ((size_t)(bb * 16 + row) * 128 + d) * 256 + tt + win * 8 + t4 * 4);
            const float vv[4] = {v.x, v.y, v.z, v.w};
            #pragma unroll
            for (int j = 0; j < 4; ++j) {
                const unsigned short hb = f2b(vv[j]);
                const int a = row * XROW + (t4 * 4 + j) * XT + d;
                xh[a] = hb;
                xl[a] = f2b(vv[j] - b2f(hb));
            }
        }
        __syncthreads();
        for (int tl = 0; tl < 8; ++tl) {
            const int t = tt + win * 8 + tl;
            bf16x8 a_h[4], a_l[4];
            #pragma unroll
            for (int ks = 0; ks < 4; ++ks) {
                a_h[ks] = *(const bf16x8*)&xh[l16 * XROW + tl * XT + ks * 32 + k0];
                a_l[ks] = *(const bf16x8*)&xl[l16 * XROW + tl * XT + ks * 32 + k0];
            }
            f32x4 acc[4];
            #pragma unroll
            for (int g = 0; g < 4; ++g)
                acc[g] = (f32x4){gb[g], gb[g], gb[g], gb[g]};
            #pragma unroll
            for (int g = 0; g < 4; ++g)
                #pragma unroll
                for (int ks = 0; ks < 4; ++ks) {
                    acc[g] = MFMA(a_h[ks], fwh[g][ks], acc[g]);
                    acc[g] = MFMA(a_h[ks], fwl[g][ks], acc[g]);
                    acc[g] = MFMA(a_l[ks], fwh[g][ks], acc[g]);
                }
            f16x8 o0, o1;
            #pragma unroll
            for (int g = 0; g < 4; ++g)
                #pragma unroll
                for (int r = 0; r < 4; ++r) {
                    const int i = g * 4 + r;
                    if (i < 8) o0[i] = (_Float16)acc[g][r];
                    else       o1[i - 8] = (_Float16)acc[g][r];
                }
            _Float16* dst = xp + ((size_t)(bb * 256 + t) * 256 + tid) * 16;
            *(f16x8*)dst = o0;
            *(f16x8*)(dst + 8) = o1;
        }
    }
}

// ================= rec: 1 barrier/step, 72 MFMA/step, LDS-chunked xp =================
// Phase t: layer1[t] + layer0[t+1] (single barrier; slot parity proven race-free).
// xp staged 4 steps/chunk, double-buffered, via global_load_lds (issued >=4
// barriers before first consumption -> vmcnt drains hit already-covered loads).
__global__ __launch_bounds__(256, 1) void rec_kernel(
    const _Float16* __restrict__ xp,
    const float* __restrict__ whh0, const float* __restrict__ wih1,
    const float* __restrict__ whh1, const float* __restrict__ bih1,
    const float* __restrict__ bhh1, const float* __restrict__ wfc,
    const float* __restrict__ bfc, float* __restrict__ out)
{
    __shared__ _Float16 xpl[2 * 4 * 4096];   // [buf][slot][4096] = 64 KB
    __shared__ unsigned short h0h[2 * HSZ], h0o[2 * HSZ], h1h[2 * HSZ], h1o[2 * HSZ];
    const int tid = threadIdx.x, lane = tid & 63, w = tid >> 6;
    const int l16 = lane & 15, quad = lane >> 4, k0 = quad * 8;
    const int bb = blockIdx.x;

    const char* gxp = (const char*)(xp + (size_t)bb * 256 * 4096);  // 8192 B per t

    // issue chunk 0 and 1 (t=0..7) while we set up
    #pragma unroll
    for (int c = 0; c < 2; ++c)
        #pragma unroll
        for (int t2 = 0; t2 < 4; ++t2) {
            const char* g = gxp + (size_t)(c * 4 + t2) * 8192 + w * 2048 + lane * 16;
            char* l = (char*)xpl + (c * 4 + t2) * 8192 + w * 2048;
            gload16(g, l);
            gload16(g + 1024, l + 1024);
        }

    bf16x8 f00h[4][2], f00l[4][2], f10h[4][2], f10l[4][2], f11h[4][2], f11l[4][2];
    float gb1[4];
    #pragma unroll
    for (int g = 0; g < 4; ++g) {
        const int n = g * 64 + w * 16 + l16;
        #pragma unroll
        for (int ks = 0; ks < 2; ++ks) {
            load_frag32(whh0, n, 64, ks * 32 + k0, f00h[g][ks], f00l[g][ks]);
            load_frag32(wih1, n, 64, ks * 32 + k0, f10h[g][ks], f10l[g][ks]);
            load_frag32(whh1, n, 64, ks * 32 + k0, f11h[g][ks], f11l[g][ks]);
        }
        gb1[g] = bih1[n] + bhh1[n];
    }
    for (int i = tid; i < 2 * HSZ; i += 256) {
        h0h[i] = 0; h0o[i] = 0; h1h[i] = 0; h1o[i] = 0;
    }
    float c0[4] = {0.f, 0.f, 0.f, 0.f}, c1[4] = {0.f, 0.f, 0.f, 0.f};

    __syncthreads();   // drains vmcnt -> chunks 0,1 resident; h bufs zeroed

    // prologue: layer0[0] (h0_init = 0) -> h0[0] slot 0 ; xp[0] in buf0 slot0
    {
        const _Float16* xv = &xpl[tid * 16];
        const f16x8 x0 = *(const f16x8*)xv;
        const f16x8 x1 = *(const f16x8*)(xv + 8);
        #pragma unroll
        for (int r = 0; r < 4; ++r) {
            const float gi = sigmoid_f((float)x0[r]);
            const float gg = tanh_f((float)x1[r]);
            const float go = sigmoid_f((float)x1[4 + r]);
            c0[r] = gi * gg;
            const float hv = go * tanh_f(c0[r]);
            const unsigned short hb = f2b(hv);
            const int idx = (quad * 4 + r) * PH + w * 16 + l16;
            h0h[idx] = hb; h0o[idx] = f2b(hv - b2f(hb));
        }
    }
    __syncthreads();

    for (int t = 0; t < 255; ++t) {
        const int s0 = t & 1, s1 = s0 ^ 1;
        const int tn = t + 1;
        if ((tn & 3) == 0) {                       // entering new chunk: prefetch cc
            const int cc = (tn >> 2) + 1;
            if (cc < 64) {
                #pragma unroll
                for (int t2 = 0; t2 < 4; ++t2) {
                    const char* g = gxp + (size_t)(cc * 4 + t2) * 8192 + w * 2048 + lane * 16;
                    char* l = (char*)xpl + ((cc & 1) * 4 + t2) * 8192 + w * 2048;
                    gload16(g, l);
                    gload16(g + 1024, l + 1024);
                }
            }
        }
        // xp[t+1] from LDS
        const _Float16* xv = &xpl[(((tn >> 2) & 1) * 4 + (tn & 3)) * 4096 + tid * 16];
        const f16x8 x0 = *(const f16x8*)xv;
        const f16x8 x1 = *(const f16x8*)(xv + 8);

        bf16x8 ah[2], ao[2], bh[2], bo[2];
        #pragma unroll
        for (int ks = 0; ks < 2; ++ks) {
            ah[ks] = *(const bf16x8*)&h0h[s0 * HSZ + l16 * PH + ks * 32 + k0];
            ao[ks] = *(const bf16x8*)&h0o[s0 * HSZ + l16 * PH + ks * 32 + k0];
            bh[ks] = *(const bf16x8*)&h1h[s1 * HSZ + l16 * PH + ks * 32 + k0];
            bo[ks] = *(const bf16x8*)&h1o[s1 * HSZ + l16 * PH + ks * 32 + k0];
        }
        f32x4 a1[4], a0[4];
        #pragma unroll
        for (int g = 0; g < 4; ++g) {
            a1[g] = (f32x4){gb1[g], gb1[g], gb1[g], gb1[g]};
            #pragma unroll
            for (int r = 0; r < 4; ++r)
                a0[g][r] = (g < 2) ? (float)x0[g * 4 + r] : (float)x1[(g - 2) * 4 + r];
        }
        #pragma unroll
        for (int g = 0; g < 4; ++g)
            #pragma unroll
            for (int ks = 0; ks < 2; ++ks) {
                a1[g] = MFMA(ah[ks], f10h[g][ks], a1[g]);
                a1[g] = MFMA(ah[ks], f10l[g][ks], a1[g]);
                a1[g] = MFMA(ao[ks], f10h[g][ks], a1[g]);
                a1[g] = MFMA(bh[ks], f11h[g][ks], a1[g]);
                a1[g] = MFMA(bh[ks], f11l[g][ks], a1[g]);
                a1[g] = MFMA(bo[ks], f11h[g][ks], a1[g]);
                a0[g] = MFMA(ah[ks], f00h[g][ks], a0[g]);
                a0[g] = MFMA(ah[ks], f00l[g][ks], a0[g]);
                a0[g] = MFMA(ao[ks], f00h[g][ks], a0[g]);
            }
        #pragma unroll
        for (int r = 0; r < 4; ++r) {
            {   // layer1[t] -> h1 slot s0
                const float gi = sigmoid_f(a1[0][r]);
                const float gf = sigmoid_f(a1[1][r]);
                const float gg = tanh_f(a1[2][r]);
                const float go = sigmoid_f(a1[3][r]);
                c1[r] = gf * c1[r] + gi * gg;
                const float hv = go * tanh_f(c1[r]);
                const unsigned short hb = f2b(hv);
                const int idx = s0 * HSZ + (quad * 4 + r) * PH + w * 16 + l16;
                h1h[idx] = hb; h1o[idx] = f2b(hv - b2f(hb));
            }
            {   // layer0[t+1] -> h0 slot s1
                const float gi = sigmoid_f(a0[0][r]);
                const float gf = sigmoid_f(a0[1][r]);
                const float gg = tanh_f(a0[2][r]);
                const float go = sigmoid_f(a0[3][r]);
                c0[r] = gf * c0[r] + gi * gg;
                const float hv = go * tanh_f(c0[r]);
                const unsigned short hb = f2b(hv);
                const int idx = s1 * HSZ + (quad * 4 + r) * PH + w * 16 + l16;
                h0h[idx] = hb; h0o[idx] = f2b(hv - b2f(hb));
            }
        }
        __syncthreads();
    }

    // epilogue: layer1[255]  (h0[255] slot 1, h1[254] slot 0) -> h1[255] slot 1
    {
        bf16x8 ah[2], ao[2], bh[2], bo[2];
        #pragma unroll
        for (int ks = 0; ks < 2; ++ks) {
            ah[ks] = *(const bf16x8*)&h0h[HSZ + l16 * PH + ks * 32 + k0];
            ao[ks] = *(const bf16x8*)&h0o[HSZ + l16 * PH + ks * 32 + k0];
            bh[ks] = *(const bf16x8*)&h1h[l16 * PH + ks * 32 + k0];
            bo[ks] = *(const bf16x8*)&h1o[l16 * PH + ks * 32 + k0];
        }
        f32x4 a1[4];
        #pragma unroll
        for (int g = 0; g < 4; ++g)
            a1[g] = (f32x4){gb1[g], gb1[g], gb1[g], gb1[g]};
        #pragma unroll
        for (int g = 0; g < 4; ++g)
            #pragma unroll
            for (int ks = 0; ks < 2; ++ks) {
                a1[g] = MFMA(ah[ks], f10h[g][ks], a1[g]);
                a1[g] = MFMA(ah[ks], f10l[g][ks], a1[g]);
                a1[g] = MFMA(ao[ks], f10h[g][ks], a1[g]);
                a1[g] = MFMA(bh[ks], f11h[g][ks], a1[g]);
                a1[g] = MFMA(bh[ks], f11l[g][ks], a1[g]);
                a1[g] = MFMA(bo[ks], f11h[g][ks], a1[g]);
            }
        #pragma unroll
        for (int r = 0; r < 4; ++r) {
            const float gi = sigmoid_f(a1[0][r]);
            const float gf = sigmoid_f(a1[1][r]);
            const float gg = tanh_f(a1[2][r]);
            const float go = sigmoid_f(a1[3][r]);
            c1[r] = gf * c1[r] + gi * gg;
            const float hv = go * tanh_f(c1[r]);
            const unsigned short hb = f2b(hv);
            const int idx = HSZ + (quad * 4 + r) * PH + w * 16 + l16;
            h1h[idx] = hb; h1o[idx] = f2b(hv - b2f(hb));
        }
    }
    __syncthreads();

    // head: scores[m][n] = sum_k h1[m][k]*wfc[n][k] + bfc[n]   (h1 final: slot 1)
    const int n  = tid & 127;
    const int mb = (tid >> 7) * 8;
    float s[8] = {0.f, 0.f, 0.f, 0.f, 0.f, 0.f, 0.f, 0.f};
    for (int k = 0; k < 64; ++k) {
        const float wv = wfc[n * 64 + k];
        #pragma unroll
        for (int m = 0; m < 8; ++m) {
            const int idx = HSZ + (mb + m) * PH + k;
            s[m] += (b2f(h1h[idx]) + b2f(h1o[idx])) * wv;
        }
    }
    #pragma unroll
    for (int m = 0; m < 8; ++m)
        out[(size_t)(bb * 16 + mb + m) * 128 + n] = s[m] + bfc[n];
}

// ================= fallback: R4's proven fused kernel (small-ws path) =================
#define XPT 136
#define XPI 4360
__global__ __launch_bounds__(256, 1) void mega_fb(
    const float* __restrict__ x,
    const float* wih0p, const float* whh0p, const float* bih0p, const float* bhh0p,
    const float* wih1p, const float* whh1p, const float* bih1p, const float* bhh1p,
    const float* wfcp, const float* bfcp, float* out)
{
    extern __shared__ __align__(16) unsigned short smem[];
    unsigned short* xs  = smem;
    unsigned short* h0h = smem + 16 * XPI;
    unsigned short* h0o = h0h + 2 * HSZ;
    unsigned short* h1h = h0h + 4 * HSZ;
    unsigned short* h1o = h0h + 6 * HSZ;

    const int tid = threadIdx.x, lane = tid & 63, w = tid >> 6;
    const int l16 = lane & 15, quad = lane >> 4;
    const int b0 = blockIdx.x * 16, k0 = quad * 8;

    bf16x8 fih0h[4][4], fih0l[4][4], fhh0h[4][2], fhh0l[4][2];
    bf16x8 fih1h[4][2], fih1l[4][2], fhh1h[4][2], fhh1l[4][2];
    float gb0r[4], gb1r[4];
    #pragma unroll
    for (int g = 0; g < 4; ++g) {
        const int n = g * 64 + w * 16 + l16;
        #pragma unroll
        for (int ks = 0; ks < 4; ++ks)
            load_frag32(wih0p, n, 128, ks * 32 + k0, fih0h[g][ks], fih0l[g][ks]);
        #pragma unroll
        for (int ks = 0; ks < 2; ++ks) {
            load_frag32(whh0p, n, 64, ks * 32 + k0, fhh0h[g][ks], fhh0l[g][ks]);
            load_frag32(wih1p, n, 64, ks * 32 + k0, fih1h[g][ks], fih1l[g][ks]);
            load_frag32(whh1p, n, 64, ks * 32 + k0, fhh1h[g][ks], fhh1l[g][ks]);
        }
        gb0r[g] = bih0p[n] + bhh0p[n];
        gb1r[g] = bih1p[n] + bhh1p[n];
    }
    for (int i = tid; i < 8 * HSZ; i += 256) h0h[i] = 0;
    float c0[4] = {0.f, 0.f, 0.f, 0.f}, c1[4] = {0.f, 0.f, 0.f, 0.f};

    for (int tc = 0; tc < 16; ++tc) {
        __syncthreads();
        for (int l = 0; l < 32; ++l) {
            const int e = l * 256 + tid;
            const int c = e & 3, d = (e >> 2) & 127, i = e >> 9;
            const float4 v = *(const float4*)(x +
                (((size_t)(b0 + i) * 128 + d) * 256 + tc * 16 + c * 4));
            const float vv[4] = {v.x, v.y, v.z, v.w};
            #pragma unroll
            for (int j = 0; j < 4; ++j) {
                const unsigned short hi = f2b(vv[j]);
                xs[i * XPI + (c * 4 + j) * XPT + d] = hi;
                xs[i * XPI + 2176 + (c * 4 + j) * XPT + d] = f2b(vv[j] - b2f(hi));
            }
        }
        __syncthreads();
        for (int tt = 0; tt < 16; ++tt) {
            const int t = tc * 16 + tt;
            const int p = t & 1, q = p ^ 1;
            bf16x8 xa[4], xo[4], hh[2], ho[2];
            #pragma unroll
            for (int ks = 0; ks < 4; ++ks) {
                xa[ks] = *(const bf16x8*)&xs[l16 * XPI + tt * XPT + ks * 32 + k0];
                xo[ks] = *(const bf16x8*)&xs[l16 * XPI + 2176 + tt * XPT + ks * 32 + k0];
            }
            #pragma unroll
            for (int ks = 0; ks < 2; ++ks) {
                hh[ks] = *(const bf16x8*)&h0h[p * HSZ + l16 * PH + ks * 32 + k0];
                ho[ks] = *(const bf16x8*)&h0o[p * HSZ + l16 * PH + ks * 32 + k0];
            }
            f32x4 acc[4];
            #pragma unroll
            for (int g = 0; g < 4; ++g)
                acc[g] = (f32x4){gb0r[g], gb0r[g], gb0r[g], gb0r[g]};
            #pragma unroll
            for (int g = 0; g < 4; ++g) {
                #pragma unroll
                for (int ks = 0; ks < 4; ++ks) {
                    acc[g] = MFMA(xa[ks], fih0h[g][ks], acc[g]);
                    acc[g] = MFMA(xa[ks], fih0l[g][ks], acc[g]);
                    acc[g] = MFMA(xo[ks], fih0h[g][ks], acc[g]);
                }
                #pragma unroll
                for (int ks = 0; ks < 2; ++ks) {
                    acc[g] = MFMA(hh[ks], fhh0h[g][ks], acc[g]);
                    acc[g] = MFMA(ho[ks], fhh0h[g][ks], acc[g]);
                    acc[g] = MFMA(hh[ks], fhh0l[g][ks], acc[g]);
                }
            }
            #pragma unroll
            for (int r = 0; r < 4; ++r) {
                const float gi = sigmoid_f(acc[0][r]);
                const float gf = sigmoid_f(acc[1][r]);
                const float gg = tanh_f(acc[2][r]);
                const float go = sigmoid_f(acc[3][r]);
                c0[r] = gf * c0[r] + gi * gg;
                const float hv = go * tanh_f(c0[r]);
                const unsigned short hb = f2b(hv);
                const int idx = q * HSZ + (quad * 4 + r) * PH + w * 16 + l16;
                h0h[idx] = hb; h0o[idx] = f2b(hv - b2f(hb));
            }
            __syncthreads();
            bf16x8 ah[2], ao[2], bh[2], bo[2];
            #pragma unroll
            for (int ks = 0; ks < 2; ++ks) {
                ah[ks] = *(const bf16x8*)&h0h[q * HSZ + l16 * PH + ks * 32 + k0];
                ao[ks] = *(const bf16x8*)&h0o[q * HSZ + l16 * PH + ks * 32 + k0];
                bh[ks] = *(const bf16x8*)&h1h[p * HSZ + l16 * PH + ks * 32 + k0];
                bo[ks] = *(const bf16x8*)&h1o[p * HSZ + l16 * PH + ks * 32 + k0];
            }
            #pragma unroll
            for (int g = 0; g < 4; ++g)
                acc[g] = (f32x4){gb1r[g], gb1r[g], gb1r[g], gb1r[g]};
            #pragma unroll
            for (int g = 0; g < 4; ++g)
                #pragma unroll
                for (int ks = 0; ks < 2; ++ks) {
                    acc[g] = MFMA(ah[ks], fih1h[g][ks], acc[g]);
                    acc[g] = MFMA(ao[ks], fih1h[g][ks], acc[g]);
                    acc[g] = MFMA(bh[ks], fhh1h[g][ks], acc[g]);
                    acc[g] = MFMA(bo[ks], fhh1h[g][ks], acc[g]);
                    acc[g] = MFMA(ah[ks], fih1l[g][ks], acc[g]);
                    acc[g] = MFMA(bh[ks], fhh1l[g][ks], acc[g]);
                }
            #pragma unroll
            for (int r = 0; r < 4; ++r) {
                const float gi = sigmoid_f(acc[0][r]);
                const float gf = sigmoid_f(acc[1][r]);
                const float gg = tanh_f(acc[2][r]);
                const float go = sigmoid_f(acc[3][r]);
                c1[r] = gf * c1[r] + gi * gg;
                const float hv = go * tanh_f(c1[r]);
                const unsigned short hb = f2b(hv);
                const int idx = q * HSZ + (quad * 4 + r) * PH + w * 16 + l16;
                h1h[idx] = hb; h1o[idx] = f2b(hv - b2f(hb));
            }
            __syncthreads();
        }
    }
    const int n = tid & 127;
    const int mb = (tid >> 7) * 8;
    float s[8] = {0.f, 0.f, 0.f, 0.f, 0.f, 0.f, 0.f, 0.f};
    for (int k = 0; k < 64; ++k) {
        const float wv = wfcp[n * 64 + k];
        #pragma unroll
        for (int m = 0; m < 8; ++m) {
            const int idx = (mb + m) * PH + k;
            s[m] += (b2f(h1h[idx]) + b2f(h1o[idx])) * wv;
        }
    }
    #pragma unroll
    for (int m = 0; m < 8; ++m)
        out[(size_t)(b0 + mb + m) * 128 + n] = s[m] + bfcp[n];
}

extern "C" void kernel_launch(void* const* d_in, const int* in_sizes, int n_in,
                              void* d_out, int out_size, void* d_ws, size_t ws_size,
                              hipStream_t stream) {
    const float* x     = (const float*)d_in[0];
    const float* wih0  = (const float*)d_in[1];
    const float* whh0  = (const float*)d_in[2];
    const float* bih0  = (const float*)d_in[3];
    const float* bhh0  = (const float*)d_in[4];
    const float* wih1  = (const float*)d_in[5];
    const float* whh1  = (const float*)d_in[6];
    const float* bih1  = (const float*)d_in[7];
    const float* bhh1  = (const float*)d_in[8];
    const float* wfc   = (const float*)d_in[9];
    const float* bfc   = (const float*)d_in[10];
    float* out = (float*)d_out;

    const size_t xp_bytes = (size_t)1024 * 256 * 256 * sizeof(_Float16); // 134 MB
    if (ws_size >= xp_bytes) {
        _Float16* xp = (_Float16*)d_ws;
        proj0_kernel<<<256, 256, 0, stream>>>(x, wih0, bih0, bhh0, xp);
        rec_kernel<<<64, 256, 0, stream>>>(xp, whh0, wih1, whh1, bih1, bhh1,
                                           wfc, bfc, out);
    } else {
        const size_t lds_bytes = (16 * XPI + 8 * HSZ) * sizeof(unsigned short);
        mega_fb<<<64, 256, lds_bytes, stream>>>(x, wih0, whh0, bih0, bhh0,
                                                wih1, whh1, bih1, bhh1, wfc, bfc, out);
    }
}

// Round 7
// 565.115 us; speedup vs baseline: 1.2551x; 1.2551x over previous
//
#include <hip/hip_runtime.h>

#define T_SEQ 256
#define PH  72
#define HSZ 1152

typedef __bf16 bf16x8 __attribute__((ext_vector_type(8)));
typedef float f32x4 __attribute__((ext_vector_type(4)));
typedef _Float16 f16x8 __attribute__((ext_vector_type(8)));

__device__ __forceinline__ float b2f(unsigned short u) {
    union { unsigned int i; float f; } v; v.i = ((unsigned int)u) << 16; return v.f;
}
__device__ __forceinline__ unsigned short f2b(float f) {
    unsigned int x = __builtin_bit_cast(unsigned int, f);
    unsigned int r = (x + 0x7fffu + ((x >> 16) & 1u)) >> 16;
    return (unsigned short)r;
}
__device__ __forceinline__ float sigmoid_f(float x) {
    float e = __builtin_amdgcn_exp2f(-1.4426950408889634f * x);
    return __builtin_amdgcn_rcpf(1.0f + e);
}
__device__ __forceinline__ float tanh_f(float x) {
    float e = __builtin_amdgcn_exp2f(-2.8853900817779268f * x);
    return 2.0f * __builtin_amdgcn_rcpf(1.0f + e) - 1.0f;
}
// fp32 weight row -> f16 hi/lo fragments (8 along k); hi+lo is fp32-faithful to ~2^-22
__device__ __forceinline__ void load_frag16(const float* wp, int n, int K, int k0,
                                            f16x8& hi, f16x8& lo) {
    const float* wf = wp + (size_t)n * K + k0;
    #pragma unroll
    for (int j = 0; j < 8; ++j) {
        const float v = wf[j];
        const _Float16 h = (_Float16)v;
        hi[j] = h;
        lo[j] = (_Float16)(v - (float)h);
    }
}
// fp32 weight row -> bf16 hi/lo (fallback kernel)
__device__ __forceinline__ void load_frag32(const float* wp, int n, int K, int k0,
                                            bf16x8& hi, bf16x8& lo) {
    const float* wf = wp + (size_t)n * K + k0;
    #pragma unroll
    for (int j = 0; j < 8; ++j) {
        const float v = wf[j];
        const unsigned short h = f2b(v);
        hi[j] = __builtin_bit_cast(__bf16, h);
        lo[j] = __builtin_bit_cast(__bf16, f2b(v - b2f(h)));
    }
}
__device__ __forceinline__ void gload16(const void* g, void* l) {
    __builtin_amdgcn_global_load_lds(
        (const __attribute__((address_space(1))) unsigned int*)g,
        (__attribute__((address_space(3))) unsigned int*)l, 16, 0, 0);
}

#define MFMA(a, b, c)   __builtin_amdgcn_mfma_f32_16x16x32_bf16(a, b, c, 0, 0, 0)
#define MFMA16(a, b, c) __builtin_amdgcn_mfma_f32_16x16x32_f16(a, b, c, 0, 0, 0)

// ================= proj0: xp fp16, bias folded =================
// per (bb,t): 4096 halves = [plane0: tid*8 -> g0,g1][plane1(+2048): tid*8 -> g2,g3]
#define XT   136
#define XROW 1096
__global__ __launch_bounds__(256) void proj0_kernel(
    const float* __restrict__ x, const float* __restrict__ wih0,
    const float* __restrict__ bih0, const float* __restrict__ bhh0,
    _Float16* __restrict__ xp)
{
    __shared__ _Float16 xh[16 * XROW];
    const int bb = blockIdx.x >> 2;
    const int tt = (blockIdx.x & 3) * 64;
    const int tid = threadIdx.x, lane = tid & 63, w = tid >> 6;
    const int l16 = lane & 15, quad = lane >> 4, k0 = quad * 8;

    f16x8 fwh[4][4], fwl[4][4];
    float gb[4];
    #pragma unroll
    for (int g = 0; g < 4; ++g) {
        const int n = g * 64 + w * 16 + l16;
        #pragma unroll
        for (int ks = 0; ks < 4; ++ks)
            load_frag16(wih0, n, 128, ks * 32 + k0, fwh[g][ks], fwl[g][ks]);
        gb[g] = bih0[n] + bhh0[n];
    }

    for (int win = 0; win < 8; ++win) {          // 8 timesteps per window
        __syncthreads();
        #pragma unroll
        for (int it = 0; it < 16; ++it) {        // 16 rows x 128 d x 8 t (fp16)
            const int e = it * 256 + tid;        // e = row*256 + d*2 + t4
            const int t4 = e & 1, d = (e >> 1) & 127, row = e >> 8;
            const float4 v = *(const float4*)(x +
                ((size_t)(bb * 16 + row) * 128 + d) * 256 + tt + win * 8 + t4 * 4);
            const float vv[4] = {v.x, v.y, v.z, v.w};
            #pragma unroll
            for (int j = 0; j < 4; ++j)
                xh[row * XROW + (t4 * 4 + j) * XT + d] = (_Float16)vv[j];
        }
        __syncthreads();
        for (int tl = 0; tl < 8; ++tl) {
            const int t = tt + win * 8 + tl;
            f16x8 a_h[4];
            #pragma unroll
            for (int ks = 0; ks < 4; ++ks)
                a_h[ks] = *(const f16x8*)&xh[l16 * XROW + tl * XT + ks * 32 + k0];
            f32x4 acc[4];
            #pragma unroll
            for (int g = 0; g < 4; ++g)
                acc[g] = (f32x4){gb[g], gb[g], gb[g], gb[g]};
            #pragma unroll
            for (int g = 0; g < 4; ++g)
                #pragma unroll
                for (int ks = 0; ks < 4; ++ks) {
                    acc[g] = MFMA16(a_h[ks], fwh[g][ks], acc[g]);
                    acc[g] = MFMA16(a_h[ks], fwl[g][ks], acc[g]);
                }
            f16x8 o0, o1;
            #pragma unroll
            for (int g = 0; g < 4; ++g)
                #pragma unroll
                for (int r = 0; r < 4; ++r) {
                    const int i = g * 4 + r;
                    if (i < 8) o0[i] = (_Float16)acc[g][r];
                    else       o1[i - 8] = (_Float16)acc[g][r];
                }
            _Float16* dst = xp + (size_t)(bb * 256 + t) * 4096 + tid * 8;
            *(f16x8*)dst = o0;
            *(f16x8*)(dst + 2048) = o1;
        }
    }
}

// ================= rec: 512 thr, wave-specialized (w<4: layer1, w>=4: layer0) =================
// Phase t: L1 waves do layer1[t] (h0[s0], h1[s1] -> h1[s0]); L0 waves do
// layer0[t+1] (h0[s0], xp[t+1] -> h0[s1]). One barrier/step. h is fp16 single
// plane; weights are f16 hi+lo (fp32-faithful). xp LDS-chunked, 4 steps x dbuf.
__global__ __launch_bounds__(512, 1) void rec_kernel(
    const _Float16* __restrict__ xp,
    const float* __restrict__ whh0, const float* __restrict__ wih1,
    const float* __restrict__ whh1, const float* __restrict__ bih1,
    const float* __restrict__ bhh1, const float* __restrict__ wfc,
    const float* __restrict__ bfc, float* __restrict__ out)
{
    __shared__ _Float16 xpl[2 * 4 * 4096];   // 64 KB
    __shared__ _Float16 h0[2 * HSZ], h1[2 * HSZ];
    const int tid = threadIdx.x, lane = tid & 63, w = tid >> 6;
    const int l16 = lane & 15, quad = lane >> 4, k0 = quad * 8;
    const int wl = w & 3;
    const bool is1 = (w < 4);
    const int bb = blockIdx.x;

    const char* gxp = (const char*)(xp + (size_t)bb * 256 * 4096);  // 8192 B / t

    if (!is1) {   // L0 waves own xp staging: chunks 0,1 now
        #pragma unroll
        for (int c = 0; c < 2; ++c)
            #pragma unroll
            for (int t2 = 0; t2 < 4; ++t2) {
                const char* g = gxp + (size_t)(c * 4 + t2) * 8192 + wl * 2048 + lane * 16;
                char* l = (char*)xpl + (c * 4 + t2) * 8192 + wl * 2048;
                gload16(g, l);
                gload16(g + 1024, l + 1024);
            }
    }

    f16x8 fAh[4][2], fAl[4][2], fBh[4][2], fBl[4][2];   // L1: ih1,hh1 ; L0: hh0 (A only)
    float gb1[4] = {0.f, 0.f, 0.f, 0.f};
    #pragma unroll
    for (int g = 0; g < 4; ++g) {
        const int n = g * 64 + wl * 16 + l16;
        if (is1) {
            #pragma unroll
            for (int ks = 0; ks < 2; ++ks) {
                load_frag16(wih1, n, 64, ks * 32 + k0, fAh[g][ks], fAl[g][ks]);
                load_frag16(whh1, n, 64, ks * 32 + k0, fBh[g][ks], fBl[g][ks]);
            }
            gb1[g] = bih1[n] + bhh1[n];
        } else {
            #pragma unroll
            for (int ks = 0; ks < 2; ++ks)
                load_frag16(whh0, n, 64, ks * 32 + k0, fAh[g][ks], fAl[g][ks]);
        }
    }
    for (int i = tid; i < 2 * HSZ; i += 512) { h0[i] = (_Float16)0.f; h1[i] = (_Float16)0.f; }
    float c[4] = {0.f, 0.f, 0.f, 0.f};     // c1 for L1 waves, c0 for L0 waves
    const int t256 = wl * 64 + lane;        // matches proj0's writer tid

    __syncthreads();   // gloads drained (chunks 0,1 resident), h zeroed

    if (!is1) {        // prologue: layer0[0] (h0_init=0) -> h0 slot 0
        const f16x8 x0 = *(const f16x8*)(xpl + t256 * 8);
        const f16x8 x1 = *(const f16x8*)(xpl + 2048 + t256 * 8);
        #pragma unroll
        for (int r = 0; r < 4; ++r) {
            const float gi = sigmoid_f((float)x0[r]);
            const float gg = tanh_f((float)x1[r]);
            const float go = sigmoid_f((float)x1[4 + r]);
            c[r] = gi * gg;
            h0[(quad * 4 + r) * PH + wl * 16 + l16] = (_Float16)(go * tanh_f(c[r]));
        }
    }
    __syncthreads();

    for (int t = 0; t < 255; ++t) {
        const int s0 = t & 1, s1 = s0 ^ 1;
        const int tn = t + 1;
        f32x4 acc[4];
        if (is1) {
            f16x8 ah[2], bh[2];
            #pragma unroll
            for (int ks = 0; ks < 2; ++ks) {
                ah[ks] = *(const f16x8*)&h0[s0 * HSZ + l16 * PH + ks * 32 + k0];
                bh[ks] = *(const f16x8*)&h1[s1 * HSZ + l16 * PH + ks * 32 + k0];
            }
            #pragma unroll
            for (int g = 0; g < 4; ++g)
                acc[g] = (f32x4){gb1[g], gb1[g], gb1[g], gb1[g]};
            #pragma unroll
            for (int g = 0; g < 4; ++g)
                #pragma unroll
                for (int ks = 0; ks < 2; ++ks) {
                    acc[g] = MFMA16(ah[ks], fAh[g][ks], acc[g]);
                    acc[g] = MFMA16(ah[ks], fAl[g][ks], acc[g]);
                    acc[g] = MFMA16(bh[ks], fBh[g][ks], acc[g]);
                    acc[g] = MFMA16(bh[ks], fBl[g][ks], acc[g]);
                }
            #pragma unroll
            for (int r = 0; r < 4; ++r) {
                const float gi = sigmoid_f(acc[0][r]);
                const float gf = sigmoid_f(acc[1][r]);
                const float gg = tanh_f(acc[2][r]);
                const float go = sigmoid_f(acc[3][r]);
                c[r] = gf * c[r] + gi * gg;
                h1[s0 * HSZ + (quad * 4 + r) * PH + wl * 16 + l16] =
                    (_Float16)(go * tanh_f(c[r]));
            }
        } else {
            if ((tn & 3) == 0) {               // prefetch next chunk
                const int cc = (tn >> 2) + 1;
                if (cc < 64) {
                    #pragma unroll
                    for (int t2 = 0; t2 < 4; ++t2) {
                        const char* g = gxp + (size_t)(cc * 4 + t2) * 8192 + wl * 2048 + lane * 16;
                        char* l = (char*)xpl + ((cc & 1) * 4 + t2) * 8192 + wl * 2048;
                        gload16(g, l);
                        gload16(g + 1024, l + 1024);
                    }
                }
            }
            const _Float16* xv = xpl + (((tn >> 2) & 1) * 4 + (tn & 3)) * 4096 + t256 * 8;
            const f16x8 x0 = *(const f16x8*)xv;
            const f16x8 x1 = *(const f16x8*)(xv + 2048);
            f16x8 ah[2];
            #pragma unroll
            for (int ks = 0; ks < 2; ++ks)
                ah[ks] = *(const f16x8*)&h0[s0 * HSZ + l16 * PH + ks * 32 + k0];
            #pragma unroll
            for (int g = 0; g < 4; ++g)
                #pragma unroll
                for (int r = 0; r < 4; ++r)
                    acc[g][r] = (g < 2) ? (float)x0[g * 4 + r] : (float)x1[(g - 2) * 4 + r];
            #pragma unroll
            for (int g = 0; g < 4; ++g)
                #pragma unroll
                for (int ks = 0; ks < 2; ++ks) {
                    acc[g] = MFMA16(ah[ks], fAh[g][ks], acc[g]);
                    acc[g] = MFMA16(ah[ks], fAl[g][ks], acc[g]);
                }
            #pragma unroll
            for (int r = 0; r < 4; ++r) {
                const float gi = sigmoid_f(acc[0][r]);
                const float gf = sigmoid_f(acc[1][r]);
                const float gg = tanh_f(acc[2][r]);
                const float go = sigmoid_f(acc[3][r]);
                c[r] = gf * c[r] + gi * gg;
                h0[s1 * HSZ + (quad * 4 + r) * PH + wl * 16 + l16] =
                    (_Float16)(go * tanh_f(c[r]));
            }
        }
        __syncthreads();
    }

    if (is1) {   // epilogue: layer1[255]  (h0 slot1, h1 slot0 -> h1 slot1)
        f16x8 ah[2], bh[2];
        #pragma unroll
        for (int ks = 0; ks < 2; ++ks) {
            ah[ks] = *(const f16x8*)&h0[HSZ + l16 * PH + ks * 32 + k0];
            bh[ks] = *(const f16x8*)&h1[l16 * PH + ks * 32 + k0];
        }
        f32x4 acc[4];
        #pragma unroll
        for (int g = 0; g < 4; ++g)
            acc[g] = (f32x4){gb1[g], gb1[g], gb1[g], gb1[g]};
        #pragma unroll
        for (int g = 0; g < 4; ++g)
            #pragma unroll
            for (int ks = 0; ks < 2; ++ks) {
                acc[g] = MFMA16(ah[ks], fAh[g][ks], acc[g]);
                acc[g] = MFMA16(ah[ks], fAl[g][ks], acc[g]);
                acc[g] = MFMA16(bh[ks], fBh[g][ks], acc[g]);
                acc[g] = MFMA16(bh[ks], fBl[g][ks], acc[g]);
            }
        #pragma unroll
        for (int r = 0; r < 4; ++r) {
            const float gi = sigmoid_f(acc[0][r]);
            const float gf = sigmoid_f(acc[1][r]);
            const float gg = tanh_f(acc[2][r]);
            const float go = sigmoid_f(acc[3][r]);
            c[r] = gf * c[r] + gi * gg;
            h1[HSZ + (quad * 4 + r) * PH + wl * 16 + l16] =
                (_Float16)(go * tanh_f(c[r]));
        }
    }
    __syncthreads();

    // head: scores[m][n] = sum_k h1_final[m][k]*wfc[n][k] + bfc[n]  (h1 slot 1)
    const int n  = tid & 127;
    const int mg = (tid >> 7) * 4;              // 4 row-groups x 4 rows
    float s[4] = {0.f, 0.f, 0.f, 0.f};
    for (int k = 0; k < 64; ++k) {
        const float wv = wfc[n * 64 + k];
        #pragma unroll
        for (int m = 0; m < 4; ++m)
            s[m] += (float)h1[HSZ + (mg + m) * PH + k] * wv;
    }
    #pragma unroll
    for (int m = 0; m < 4; ++m)
        out[(size_t)(bb * 16 + mg + m) * 128 + n] = s[m] + bfc[n];
}

// ================= fallback: R4's proven fused kernel (small-ws path) =================
#define XPT 136
#define XPI 4360
__global__ __launch_bounds__(256, 1) void mega_fb(
    const float* __restrict__ x,
    const float* wih0p, const float* whh0p, const float* bih0p, const float* bhh0p,
    const float* wih1p, const float* whh1p, const float* bih1p, const float* bhh1p,
    const float* wfcp, const float* bfcp, float* out)
{
    extern __shared__ __align__(16) unsigned short smem[];
    unsigned short* xs  = smem;
    unsigned short* h0h = smem + 16 * XPI;
    unsigned short* h0o = h0h + 2 * HSZ;
    unsigned short* h1h = h0h + 4 * HSZ;
    unsigned short* h1o = h0h + 6 * HSZ;

    const int tid = threadIdx.x, lane = tid & 63, w = tid >> 6;
    const int l16 = lane & 15, quad = lane >> 4;
    const int b0 = blockIdx.x * 16, k0 = quad * 8;

    bf16x8 fih0h[4][4], fih0l[4][4], fhh0h[4][2], fhh0l[4][2];
    bf16x8 fih1h[4][2], fih1l[4][2], fhh1h[4][2], fhh1l[4][2];
    float gb0r[4], gb1r[4];
    #pragma unroll
    for (int g = 0; g < 4; ++g) {
        const int n = g * 64 + w * 16 + l16;
        #pragma unroll
        for (int ks = 0; ks < 4; ++ks)
            load_frag32(wih0p, n, 128, ks * 32 + k0, fih0h[g][ks], fih0l[g][ks]);
        #pragma unroll
        for (int ks = 0; ks < 2; ++ks) {
            load_frag32(whh0p, n, 64, ks * 32 + k0, fhh0h[g][ks], fhh0l[g][ks]);
            load_frag32(wih1p, n, 64, ks * 32 + k0, fih1h[g][ks], fih1l[g][ks]);
            load_frag32(whh1p, n, 64, ks * 32 + k0, fhh1h[g][ks], fhh1l[g][ks]);
        }
        gb0r[g] = bih0p[n] + bhh0p[n];
        gb1r[g] = bih1p[n] + bhh1p[n];
    }
    for (int i = tid; i < 8 * HSZ; i += 256) h0h[i] = 0;
    float c0[4] = {0.f, 0.f, 0.f, 0.f}, c1[4] = {0.f, 0.f, 0.f, 0.f};

    for (int tc = 0; tc < 16; ++tc) {
        __syncthreads();
        for (int l = 0; l < 32; ++l) {
            const int e = l * 256 + tid;
            const int c = e & 3, d = (e >> 2) & 127, i = e >> 9;
            const float4 v = *(const float4*)(x +
                (((size_t)(b0 + i) * 128 + d) * 256 + tc * 16 + c * 4));
            const float vv[4] = {v.x, v.y, v.z, v.w};
            #pragma unroll
            for (int j = 0; j < 4; ++j) {
                const unsigned short hi = f2b(vv[j]);
                xs[i * XPI + (c * 4 + j) * XPT + d] = hi;
                xs[i * XPI + 2176 + (c * 4 + j) * XPT + d] = f2b(vv[j] - b2f(hi));
            }
        }
        __syncthreads();
        for (int tt = 0; tt < 16; ++tt) {
            const int t = tc * 16 + tt;
            const int p = t & 1, q = p ^ 1;
            bf16x8 xa[4], xo[4], hh[2], ho[2];
            #pragma unroll
            for (int ks = 0; ks < 4; ++ks) {
                xa[ks] = *(const bf16x8*)&xs[l16 * XPI + tt * XPT + ks * 32 + k0];
                xo[ks] = *(const bf16x8*)&xs[l16 * XPI + 2176 + tt * XPT + ks * 32 + k0];
            }
            #pragma unroll
            for (int ks = 0; ks < 2; ++ks) {
                hh[ks] = *(const bf16x8*)&h0h[p * HSZ + l16 * PH + ks * 32 + k0];
                ho[ks] = *(const bf16x8*)&h0o[p * HSZ + l16 * PH + ks * 32 + k0];
            }
            f32x4 acc[4];
            #pragma unroll
            for (int g = 0; g < 4; ++g)
                acc[g] = (f32x4){gb0r[g], gb0r[g], gb0r[g], gb0r[g]};
            #pragma unroll
            for (int g = 0; g < 4; ++g) {
                #pragma unroll
                for (int ks = 0; ks < 4; ++ks) {
                    acc[g] = MFMA(xa[ks], fih0h[g][ks], acc[g]);
                    acc[g] = MFMA(xa[ks], fih0l[g][ks], acc[g]);
                    acc[g] = MFMA(xo[ks], fih0h[g][ks], acc[g]);
                }
                #pragma unroll
                for (int ks = 0; ks < 2; ++ks) {
                    acc[g] = MFMA(hh[ks], fhh0h[g][ks], acc[g]);
                    acc[g] = MFMA(ho[ks], fhh0h[g][ks], acc[g]);
                    acc[g] = MFMA(hh[ks], fhh0l[g][ks], acc[g]);
                }
            }
            #pragma unroll
            for (int r = 0; r < 4; ++r) {
                const float gi = sigmoid_f(acc[0][r]);
                const float gf = sigmoid_f(acc[1][r]);
                const float gg = tanh_f(acc[2][r]);
                const float go = sigmoid_f(acc[3][r]);
                c0[r] = gf * c0[r] + gi * gg;
                const float hv = go * tanh_f(c0[r]);
                const unsigned short hb = f2b(hv);
                const int idx = q * HSZ + (quad * 4 + r) * PH + w * 16 + l16;
                h0h[idx] = hb; h0o[idx] = f2b(hv - b2f(hb));
            }
            __syncthreads();
            bf16x8 ah[2], ao[2], bh[2], bo[2];
            #pragma unroll
            for (int ks = 0; ks < 2; ++ks) {
                ah[ks] = *(const bf16x8*)&h0h[q * HSZ + l16 * PH + ks * 32 + k0];
                ao[ks] = *(const bf16x8*)&h0o[q * HSZ + l16 * PH + ks * 32 + k0];
                bh[ks] = *(const bf16x8*)&h1h[p * HSZ + l16 * PH + ks * 32 + k0];
                bo[ks] = *(const bf16x8*)&h1o[p * HSZ + l16 * PH + ks * 32 + k0];
            }
            #pragma unroll
            for (int g = 0; g < 4; ++g)
                acc[g] = (f32x4){gb1r[g], gb1r[g], gb1r[g], gb1r[g]};
            #pragma unroll
            for (int g = 0; g < 4; ++g)
                #pragma unroll
                for (int ks = 0; ks < 2; ++ks) {
                    acc[g] = MFMA(ah[ks], fih1h[g][ks], acc[g]);
                    acc[g] = MFMA(ao[ks], fih1h[g][ks], acc[g]);
                    acc[g] = MFMA(bh[ks], fhh1h[g][ks], acc[g]);
                    acc[g] = MFMA(bo[ks], fhh1h[g][ks], acc[g]);
                    acc[g] = MFMA(ah[ks], fih1l[g][ks], acc[g]);
                    acc[g] = MFMA(bh[ks], fhh1l[g][ks], acc[g]);
                }
            #pragma unroll
            for (int r = 0; r < 4; ++r) {
                const float gi = sigmoid_f(acc[0][r]);
                const float gf = sigmoid_f(acc[1][r]);
                const float gg = tanh_f(acc[2][r]);
                const float go = sigmoid_f(acc[3][r]);
                c1[r] = gf * c1[r] + gi * gg;
                const float hv = go * tanh_f(c1[r]);
                const unsigned short hb = f2b(hv);
                const int idx = q * HSZ + (quad * 4 + r) * PH + w * 16 + l16;
                h1h[idx] = hb; h1o[idx] = f2b(hv - b2f(hb));
            }
            __syncthreads();
        }
    }
    const int n = tid & 127;
    const int mb = (tid >> 7) * 8;
    float s[8] = {0.f, 0.f, 0.f, 0.f, 0.f, 0.f, 0.f, 0.f};
    for (int k = 0; k < 64; ++k) {
        const float wv = wfcp[n * 64 + k];
        #pragma unroll
        for (int m = 0; m < 8; ++m) {
            const int idx = (mb + m) * PH + k;
            s[m] += (b2f(h1h[idx]) + b2f(h1o[idx])) * wv;
        }
    }
    #pragma unroll
    for (int m = 0; m < 8; ++m)
        out[(size_t)(b0 + mb + m) * 128 + n] = s[m] + bfcp[n];
}

extern "C" void kernel_launch(void* const* d_in, const int* in_sizes, int n_in,
                              void* d_out, int out_size, void* d_ws, size_t ws_size,
                              hipStream_t stream) {
    const float* x     = (const float*)d_in[0];
    const float* wih0  = (const float*)d_in[1];
    const float* whh0  = (const float*)d_in[2];
    const float* bih0  = (const float*)d_in[3];
    const float* bhh0  = (const float*)d_in[4];
    const float* wih1  = (const float*)d_in[5];
    const float* whh1  = (const float*)d_in[6];
    const float* bih1  = (const float*)d_in[7];
    const float* bhh1  = (const float*)d_in[8];
    const float* wfc   = (const float*)d_in[9];
    const float* bfc   = (const float*)d_in[10];
    float* out = (float*)d_out;

    const size_t xp_bytes = (size_t)1024 * 256 * 256 * sizeof(_Float16); // 134 MB
    if (ws_size >= xp_bytes) {
        _Float16* xp = (_Float16*)d_ws;
        proj0_kernel<<<256, 256, 0, stream>>>(x, wih0, bih0, bhh0, xp);
        rec_kernel<<<64, 512, 0, stream>>>(xp, whh0, wih1, whh1, bih1, bhh1,
                                           wfc, bfc, out);
    } else {
        const size_t lds_bytes = (16 * XPI + 8 * HSZ) * sizeof(unsigned short);
        mega_fb<<<64, 256, lds_bytes, stream>>>(x, wih0, whh0, bih0, bhh0,
                                                wih1, whh1, bih1, bhh1, wfc, bfc, out);
    }
}

// Round 8
// 499.538 us; speedup vs baseline: 1.4199x; 1.1313x over previous
//
#include <hip/hip_runtime.h>

#define T_SEQ 256
#define PH  72
#define HSZ 1152

typedef __bf16 bf16x8 __attribute__((ext_vector_type(8)));
typedef float f32x4 __attribute__((ext_vector_type(4)));
typedef _Float16 f16x8 __attribute__((ext_vector_type(8)));
typedef _Float16 f16x2 __attribute__((ext_vector_type(2)));

__device__ __forceinline__ float b2f(unsigned short u) {
    union { unsigned int i; float f; } v; v.i = ((unsigned int)u) << 16; return v.f;
}
__device__ __forceinline__ unsigned short f2b(float f) {
    unsigned int x = __builtin_bit_cast(unsigned int, f);
    unsigned int r = (x + 0x7fffu + ((x >> 16) & 1u)) >> 16;
    return (unsigned short)r;
}
__device__ __forceinline__ float sigmoid_f(float x) {
    float e = __builtin_amdgcn_exp2f(-1.4426950408889634f * x);
    return __builtin_amdgcn_rcpf(1.0f + e);
}
__device__ __forceinline__ float tanh_f(float x) {
    float e = __builtin_amdgcn_exp2f(-2.8853900817779268f * x);
    return 2.0f * __builtin_amdgcn_rcpf(1.0f + e) - 1.0f;
}
__device__ __forceinline__ void load_frag16(const float* wp, int n, int K, int k0,
                                            f16x8& hi, f16x8& lo) {
    const float* wf = wp + (size_t)n * K + k0;
    #pragma unroll
    for (int j = 0; j < 8; ++j) {
        const float v = wf[j];
        const _Float16 h = (_Float16)v;
        hi[j] = h;
        lo[j] = (_Float16)(v - (float)h);
    }
}
__device__ __forceinline__ void load_frag32(const float* wp, int n, int K, int k0,
                                            bf16x8& hi, bf16x8& lo) {
    const float* wf = wp + (size_t)n * K + k0;
    #pragma unroll
    for (int j = 0; j < 8; ++j) {
        const float v = wf[j];
        const unsigned short h = f2b(v);
        hi[j] = __builtin_bit_cast(__bf16, h);
        lo[j] = __builtin_bit_cast(__bf16, f2b(v - b2f(h)));
    }
}
__device__ __forceinline__ void gload16(const void* g, void* l) {
    __builtin_amdgcn_global_load_lds(
        (const __attribute__((address_space(1))) unsigned int*)g,
        (__attribute__((address_space(3))) unsigned int*)l, 16, 0, 0);
}

#define MFMA(a, b, c)   __builtin_amdgcn_mfma_f32_16x16x32_bf16(a, b, c, 0, 0, 0)
#define MFMA16(a, b, c) __builtin_amdgcn_mfma_f32_16x16x32_f16(a, b, c, 0, 0, 0)

// ================= proj0 v2: 512 blocks x 512 thr (2 blocks/CU) =================
// xp[bb][t] (4096 halves): gp*2048 + (wl*64+quad*16+l16)*8 + gg*4 + r.
// 8 waves: wl = wv>>1 (n-slice), gp = wv&1 (g-pair). One 16-B store per t/wave.
#define XT   136
#define XROW 1096
__global__ __launch_bounds__(512, 4) void proj0_kernel(
    const float* __restrict__ x, const float* __restrict__ wih0,
    const float* __restrict__ bih0, const float* __restrict__ bhh0,
    _Float16* __restrict__ xp)
{
    __shared__ _Float16 xh[16 * XROW];
    const int bb  = blockIdx.x >> 3;
    const int tch = (blockIdx.x & 7) * 32;
    const int tid = threadIdx.x, lane = tid & 63, wv = tid >> 6;
    const int l16 = lane & 15, quad = lane >> 4, k0 = quad * 8;
    const int wl = wv >> 1, gp = wv & 1;

    f16x8 fwh[2][4], fwl[2][4];
    float gb[2];
    #pragma unroll
    for (int gg = 0; gg < 2; ++gg) {
        const int n = (gp * 2 + gg) * 64 + wl * 16 + l16;
        #pragma unroll
        for (int ks = 0; ks < 4; ++ks)
            load_frag16(wih0, n, 128, ks * 32 + k0, fwh[gg][ks], fwl[gg][ks]);
        gb[gg] = bih0[n] + bhh0[n];
    }

    for (int win = 0; win < 4; ++win) {          // 4 windows x 8 timesteps
        __syncthreads();
        #pragma unroll
        for (int it = 0; it < 8; ++it) {         // stage 16 rows x 128 d x 8 t
            const int e = it * 512 + tid;        // e = row*256 + d*2 + t4
            const int t4 = e & 1, d = (e >> 1) & 127, row = e >> 8;
            const float4 v = *(const float4*)(x +
                ((size_t)(bb * 16 + row) * 128 + d) * 256 + tch + win * 8 + t4 * 4);
            const float vv[4] = {v.x, v.y, v.z, v.w};
            #pragma unroll
            for (int j = 0; j < 4; ++j)
                xh[row * XROW + (t4 * 4 + j) * XT + d] = (_Float16)vv[j];
        }
        __syncthreads();
        for (int tl = 0; tl < 8; ++tl) {
            const int t = tch + win * 8 + tl;
            f16x8 a_h[4];
            #pragma unroll
            for (int ks = 0; ks < 4; ++ks)
                a_h[ks] = *(const f16x8*)&xh[l16 * XROW + tl * XT + ks * 32 + k0];
            f32x4 acc[2];
            #pragma unroll
            for (int gg = 0; gg < 2; ++gg)
                acc[gg] = (f32x4){gb[gg], gb[gg], gb[gg], gb[gg]};
            #pragma unroll
            for (int gg = 0; gg < 2; ++gg)
                #pragma unroll
                for (int ks = 0; ks < 4; ++ks) {
                    acc[gg] = MFMA16(a_h[ks], fwh[gg][ks], acc[gg]);
                    acc[gg] = MFMA16(a_h[ks], fwl[gg][ks], acc[gg]);
                }
            f16x8 o0;
            #pragma unroll
            for (int gg = 0; gg < 2; ++gg)
                #pragma unroll
                for (int r = 0; r < 4; ++r)
                    o0[gg * 4 + r] = (_Float16)acc[gg][r];
            *(f16x8*)(xp + (size_t)(bb * 256 + t) * 4096 + gp * 2048
                      + (wl * 64 + quad * 16 + l16) * 8) = o0;
        }
    }
}

// ================= rec v3: 128 blocks x 8 real rows x 512 thr =================
// Real rows at C-register rows m = quad*4+r, r<2 (global row bb2*8+quad*2+r):
// act r-loop runs 2 not 4 -> trans issue per CU halves; MFMA/SIMD unchanged;
// 128 CUs active. Pad A-rows stay zero. xp gathered from proj0 layout.
__global__ __launch_bounds__(512, 2) void rec_kernel(
    const _Float16* __restrict__ xp,
    const float* __restrict__ whh0, const float* __restrict__ wih1,
    const float* __restrict__ whh1, const float* __restrict__ bih1,
    const float* __restrict__ bhh1, const float* __restrict__ wfc,
    const float* __restrict__ bfc, float* __restrict__ out)
{
    __shared__ _Float16 xpl[2 * 4 * 2048];   // 32 KB: [buf][t&3][2048]
    __shared__ _Float16 h0[2 * HSZ], h1[2 * HSZ];
    const int tid = threadIdx.x, lane = tid & 63, w = tid >> 6;
    const int l16 = lane & 15, quad = lane >> 4, k0 = quad * 8;
    const int wl = w & 3;
    const bool is1 = (w < 4);
    const int bb2 = blockIdx.x;
    const int h8 = bb2 & 1;

    const char* gxp = (const char*)(xp + (size_t)(bb2 >> 1) * 256 * 4096); // 8192 B/t
    const int laneOff = (lane >> 5) * 4096
                      + (wl * 64 + (h8 * 2 + ((lane >> 4) & 1)) * 16 + (lane & 15)) * 16;

    if (!is1) {   // L0 waves stage chunks 0,1 (t=0..7): 1 gload16 per t
        #pragma unroll
        for (int t = 0; t < 8; ++t)
            gload16(gxp + (size_t)t * 8192 + laneOff,
                    (char*)xpl + t * 4096 + wl * 1024);
    }

    f16x8 fAh[4][2], fAl[4][2], fBh[4][2], fBl[4][2];
    float gb1[4] = {0.f, 0.f, 0.f, 0.f};
    #pragma unroll
    for (int g = 0; g < 4; ++g) {
        const int n = g * 64 + wl * 16 + l16;
        if (is1) {
            #pragma unroll
            for (int ks = 0; ks < 2; ++ks) {
                load_frag16(wih1, n, 64, ks * 32 + k0, fAh[g][ks], fAl[g][ks]);
                load_frag16(whh1, n, 64, ks * 32 + k0, fBh[g][ks], fBl[g][ks]);
            }
            gb1[g] = bih1[n] + bhh1[n];
        } else {
            #pragma unroll
            for (int ks = 0; ks < 2; ++ks)
                load_frag16(whh0, n, 64, ks * 32 + k0, fAh[g][ks], fAl[g][ks]);
        }
    }
    for (int i = tid; i < 2 * HSZ; i += 512) { h0[i] = (_Float16)0.f; h1[i] = (_Float16)0.f; }
    float c[2] = {0.f, 0.f};
    const int d2 = (quad & 1) * 2;
    const int chunkBase = wl * 512 + ((quad >> 1) * 16 + l16) * 8;  // halves (p=0)

    __syncthreads();

    if (!is1) {        // prologue: layer0[0] (h0_init=0) -> h0 slot 0
        const f16x2 i01 = *(const f16x2*)&xpl[chunkBase + d2];
        const f16x2 g01 = *(const f16x2*)&xpl[chunkBase + 256 + d2];
        const f16x2 o01 = *(const f16x2*)&xpl[chunkBase + 256 + 4 + d2];
        #pragma unroll
        for (int r = 0; r < 2; ++r) {
            const float gi = sigmoid_f((float)i01[r]);
            const float gg = tanh_f((float)g01[r]);
            const float go = sigmoid_f((float)o01[r]);
            c[r] = gi * gg;
            h0[(quad * 4 + r) * PH + wl * 16 + l16] = (_Float16)(go * tanh_f(c[r]));
        }
    }
    __syncthreads();

    for (int t = 0; t < 255; ++t) {
        const int s0 = t & 1, s1 = s0 ^ 1;
        const int tn = t + 1;
        if (is1) {
            f16x8 ah[2], bh[2];
            #pragma unroll
            for (int ks = 0; ks < 2; ++ks) {
                ah[ks] = *(const f16x8*)&h0[s0 * HSZ + l16 * PH + ks * 32 + k0];
                bh[ks] = *(const f16x8*)&h1[s1 * HSZ + l16 * PH + ks * 32 + k0];
            }
            f32x4 acc[4];
            #pragma unroll
            for (int g = 0; g < 4; ++g)
                acc[g] = (f32x4){gb1[g], gb1[g], gb1[g], gb1[g]};
            #pragma unroll
            for (int g = 0; g < 4; ++g)
                #pragma unroll
                for (int ks = 0; ks < 2; ++ks) {
                    acc[g] = MFMA16(ah[ks], fAh[g][ks], acc[g]);
                    acc[g] = MFMA16(ah[ks], fAl[g][ks], acc[g]);
                    acc[g] = MFMA16(bh[ks], fBh[g][ks], acc[g]);
                    acc[g] = MFMA16(bh[ks], fBl[g][ks], acc[g]);
                }
            #pragma unroll
            for (int r = 0; r < 2; ++r) {
                const float gi = sigmoid_f(acc[0][r]);
                const float gf = sigmoid_f(acc[1][r]);
                const float gg = tanh_f(acc[2][r]);
                const float go = sigmoid_f(acc[3][r]);
                c[r] = gf * c[r] + gi * gg;
                h1[s0 * HSZ + (quad * 4 + r) * PH + wl * 16 + l16] =
                    (_Float16)(go * tanh_f(c[r]));
            }
        } else {
            if ((tn & 3) == 0) {               // prefetch next 4-step chunk
                const int cc = (tn >> 2) + 1;
                if (cc < 64) {
                    #pragma unroll
                    for (int t2 = 0; t2 < 4; ++t2)
                        gload16(gxp + (size_t)(cc * 4 + t2) * 8192 + laneOff,
                                (char*)xpl + ((cc & 1) * 4 + t2) * 4096 + wl * 1024);
                }
            }
            const int sb = (((tn >> 2) & 1) * 4 + (tn & 3)) * 2048 + chunkBase;
            const f16x2 i01 = *(const f16x2*)&xpl[sb + d2];
            const f16x2 f01 = *(const f16x2*)&xpl[sb + 4 + d2];
            const f16x2 g01 = *(const f16x2*)&xpl[sb + 256 + d2];
            const f16x2 o01 = *(const f16x2*)&xpl[sb + 256 + 4 + d2];
            f16x8 ah[2];
            #pragma unroll
            for (int ks = 0; ks < 2; ++ks)
                ah[ks] = *(const f16x8*)&h0[s0 * HSZ + l16 * PH + ks * 32 + k0];
            f32x4 acc[4];
            acc[0] = (f32x4){(float)i01[0], (float)i01[1], 0.f, 0.f};
            acc[1] = (f32x4){(float)f01[0], (float)f01[1], 0.f, 0.f};
            acc[2] = (f32x4){(float)g01[0], (float)g01[1], 0.f, 0.f};
            acc[3] = (f32x4){(float)o01[0], (float)o01[1], 0.f, 0.f};
            #pragma unroll
            for (int g = 0; g < 4; ++g)
                #pragma unroll
                for (int ks = 0; ks < 2; ++ks) {
                    acc[g] = MFMA16(ah[ks], fAh[g][ks], acc[g]);
                    acc[g] = MFMA16(ah[ks], fAl[g][ks], acc[g]);
                }
            #pragma unroll
            for (int r = 0; r < 2; ++r) {
                const float gi = sigmoid_f(acc[0][r]);
                const float gf = sigmoid_f(acc[1][r]);
                const float gg = tanh_f(acc[2][r]);
                const float go = sigmoid_f(acc[3][r]);
                c[r] = gf * c[r] + gi * gg;
                h0[s1 * HSZ + (quad * 4 + r) * PH + wl * 16 + l16] =
                    (_Float16)(go * tanh_f(c[r]));
            }
        }
        __syncthreads();
    }

    if (is1) {   // epilogue: layer1[255] (h0 slot1, h1 slot0 -> h1 slot1)
        f16x8 ah[2], bh[2];
        #pragma unroll
        for (int ks = 0; ks < 2; ++ks) {
            ah[ks] = *(const f16x8*)&h0[HSZ + l16 * PH + ks * 32 + k0];
            bh[ks] = *(const f16x8*)&h1[l16 * PH + ks * 32 + k0];
        }
        f32x4 acc[4];
        #pragma unroll
        for (int g = 0; g < 4; ++g)
            acc[g] = (f32x4){gb1[g], gb1[g], gb1[g], gb1[g]};
        #pragma unroll
        for (int g = 0; g < 4; ++g)
            #pragma unroll
            for (int ks = 0; ks < 2; ++ks) {
                acc[g] = MFMA16(ah[ks], fAh[g][ks], acc[g]);
                acc[g] = MFMA16(ah[ks], fAl[g][ks], acc[g]);
                acc[g] = MFMA16(bh[ks], fBh[g][ks], acc[g]);
                acc[g] = MFMA16(bh[ks], fBl[g][ks], acc[g]);
            }
        #pragma unroll
        for (int r = 0; r < 2; ++r) {
            const float gi = sigmoid_f(acc[0][r]);
            const float gf = sigmoid_f(acc[1][r]);
            const float gg = tanh_f(acc[2][r]);
            const float go = sigmoid_f(acc[3][r]);
            c[r] = gf * c[r] + gi * gg;
            h1[HSZ + (quad * 4 + r) * PH + wl * 16 + l16] =
                (_Float16)(go * tanh_f(c[r]));
        }
    }
    __syncthreads();

    // head: out[bb2*8 + sel*2 + r2][n], h1 row m = sel*4 + r2 (slot 1)
    const int n   = tid & 127;
    const int sel = tid >> 7;
    float s[2] = {0.f, 0.f};
    for (int k = 0; k < 64; ++k) {
        const float wv = wfc[n * 64 + k];
        #pragma unroll
        for (int r2 = 0; r2 < 2; ++r2)
            s[r2] += (float)h1[HSZ + (sel * 4 + r2) * PH + k] * wv;
    }
    #pragma unroll
    for (int r2 = 0; r2 < 2; ++r2)
        out[(size_t)(bb2 * 8 + sel * 2 + r2) * 128 + n] = s[r2] + bfc[n];
}

// ================= fallback: R4's proven fused kernel (small-ws path) =================
#define XPT 136
#define XPI 4360
__global__ __launch_bounds__(256, 1) void mega_fb(
    const float* __restrict__ x,
    const float* wih0p, const float* whh0p, const float* bih0p, const float* bhh0p,
    const float* wih1p, const float* whh1p, const float* bih1p, const float* bhh1p,
    const float* wfcp, const float* bfcp, float* out)
{
    extern __shared__ __align__(16) unsigned short smem[];
    unsigned short* xs  = smem;
    unsigned short* h0h = smem + 16 * XPI;
    unsigned short* h0o = h0h + 2 * HSZ;
    unsigned short* h1h = h0h + 4 * HSZ;
    unsigned short* h1o = h0h + 6 * HSZ;

    const int tid = threadIdx.x, lane = tid & 63, w = tid >> 6;
    const int l16 = lane & 15, quad = lane >> 4;
    const int b0 = blockIdx.x * 16, k0 = quad * 8;

    bf16x8 fih0h[4][4], fih0l[4][4], fhh0h[4][2], fhh0l[4][2];
    bf16x8 fih1h[4][2], fih1l[4][2], fhh1h[4][2], fhh1l[4][2];
    float gb0r[4], gb1r[4];
    #pragma unroll
    for (int g = 0; g < 4; ++g) {
        const int n = g * 64 + w * 16 + l16;
        #pragma unroll
        for (int ks = 0; ks < 4; ++ks)
            load_frag32(wih0p, n, 128, ks * 32 + k0, fih0h[g][ks], fih0l[g][ks]);
        #pragma unroll
        for (int ks = 0; ks < 2; ++ks) {
            load_frag32(whh0p, n, 64, ks * 32 + k0, fhh0h[g][ks], fhh0l[g][ks]);
            load_frag32(wih1p, n, 64, ks * 32 + k0, fih1h[g][ks], fih1l[g][ks]);
            load_frag32(whh1p, n, 64, ks * 32 + k0, fhh1h[g][ks], fhh1l[g][ks]);
        }
        gb0r[g] = bih0p[n] + bhh0p[n];
        gb1r[g] = bih1p[n] + bhh1p[n];
    }
    for (int i = tid; i < 8 * HSZ; i += 256) h0h[i] = 0;
    float c0[4] = {0.f, 0.f, 0.f, 0.f}, c1[4] = {0.f, 0.f, 0.f, 0.f};

    for (int tc = 0; tc < 16; ++tc) {
        __syncthreads();
        for (int l = 0; l < 32; ++l) {
            const int e = l * 256 + tid;
            const int cc = e & 3, d = (e >> 2) & 127, i = e >> 9;
            const float4 v = *(const float4*)(x +
                (((size_t)(b0 + i) * 128 + d) * 256 + tc * 16 + cc * 4));
            const float vv[4] = {v.x, v.y, v.z, v.w};
            #pragma unroll
            for (int j = 0; j < 4; ++j) {
                const unsigned short hi = f2b(vv[j]);
                xs[i * XPI + (cc * 4 + j) * XPT + d] = hi;
                xs[i * XPI + 2176 + (cc * 4 + j) * XPT + d] = f2b(vv[j] - b2f(hi));
            }
        }
        __syncthreads();
        for (int tt = 0; tt < 16; ++tt) {
            const int t = tc * 16 + tt;
            const int p = t & 1, q = p ^ 1;
            bf16x8 xa[4], xo[4], hh[2], ho[2];
            #pragma unroll
            for (int ks = 0; ks < 4; ++ks) {
                xa[ks] = *(const bf16x8*)&xs[l16 * XPI + tt * XPT + ks * 32 + k0];
                xo[ks] = *(const bf16x8*)&xs[l16 * XPI + 2176 + tt * XPT + ks * 32 + k0];
            }
            #pragma unroll
            for (int ks = 0; ks < 2; ++ks) {
                hh[ks] = *(const bf16x8*)&h0h[p * HSZ + l16 * PH + ks * 32 + k0];
                ho[ks] = *(const bf16x8*)&h0o[p * HSZ + l16 * PH + ks * 32 + k0];
            }
            f32x4 acc[4];
            #pragma unroll
            for (int g = 0; g < 4; ++g)
                acc[g] = (f32x4){gb0r[g], gb0r[g], gb0r[g], gb0r[g]};
            #pragma unroll
            for (int g = 0; g < 4; ++g) {
                #pragma unroll
                for (int ks = 0; ks < 4; ++ks) {
                    acc[g] = MFMA(xa[ks], fih0h[g][ks], acc[g]);
                    acc[g] = MFMA(xa[ks], fih0l[g][ks], acc[g]);
                    acc[g] = MFMA(xo[ks], fih0h[g][ks], acc[g]);
                }
                #pragma unroll
                for (int ks = 0; ks < 2; ++ks) {
                    acc[g] = MFMA(hh[ks], fhh0h[g][ks], acc[g]);
                    acc[g] = MFMA(ho[ks], fhh0h[g][ks], acc[g]);
                    acc[g] = MFMA(hh[ks], fhh0l[g][ks], acc[g]);
                }
            }
            #pragma unroll
            for (int r = 0; r < 4; ++r) {
                const float gi = sigmoid_f(acc[0][r]);
                const float gf = sigmoid_f(acc[1][r]);
                const float gg = tanh_f(acc[2][r]);
                const float go = sigmoid_f(acc[3][r]);
                c0[r] = gf * c0[r] + gi * gg;
                const float hv = go * tanh_f(c0[r]);
                const unsigned short hb = f2b(hv);
                const int idx = q * HSZ + (quad * 4 + r) * PH + w * 16 + l16;
                h0h[idx] = hb; h0o[idx] = f2b(hv - b2f(hb));
            }
            __syncthreads();
            bf16x8 ah[2], ao[2], bh[2], bo[2];
            #pragma unroll
            for (int ks = 0; ks < 2; ++ks) {
                ah[ks] = *(const bf16x8*)&h0h[q * HSZ + l16 * PH + ks * 32 + k0];
                ao[ks] = *(const bf16x8*)&h0o[q * HSZ + l16 * PH + ks * 32 + k0];
                bh[ks] = *(const bf16x8*)&h1h[p * HSZ + l16 * PH + ks * 32 + k0];
                bo[ks] = *(const bf16x8*)&h1o[p * HSZ + l16 * PH + ks * 32 + k0];
            }
            #pragma unroll
            for (int g = 0; g < 4; ++g)
                acc[g] = (f32x4){gb1r[g], gb1r[g], gb1r[g], gb1r[g]};
            #pragma unroll
            for (int g = 0; g < 4; ++g)
                #pragma unroll
                for (int ks = 0; ks < 2; ++ks) {
                    acc[g] = MFMA(ah[ks], fih1h[g][ks], acc[g]);
                    acc[g] = MFMA(ao[ks], fih1h[g][ks], acc[g]);
                    acc[g] = MFMA(bh[ks], fhh1h[g][ks], acc[g]);
                    acc[g] = MFMA(bo[ks], fhh1h[g][ks], acc[g]);
                    acc[g] = MFMA(ah[ks], fih1l[g][ks], acc[g]);
                    acc[g] = MFMA(bh[ks], fhh1l[g][ks], acc[g]);
                }
            #pragma unroll
            for (int r = 0; r < 4; ++r) {
                const float gi = sigmoid_f(acc[0][r]);
                const float gf = sigmoid_f(acc[1][r]);
                const float gg = tanh_f(acc[2][r]);
                const float go = sigmoid_f(acc[3][r]);
                c1[r] = gf * c1[r] + gi * gg;
                const float hv = go * tanh_f(c1[r]);
                const unsigned short hb = f2b(hv);
                const int idx = q * HSZ + (quad * 4 + r) * PH + w * 16 + l16;
                h1h[idx] = hb; h1o[idx] = f2b(hv - b2f(hb));
            }
            __syncthreads();
        }
    }
    const int n = tid & 127;
    const int mb = (tid >> 7) * 8;
    float s[8] = {0.f, 0.f, 0.f, 0.f, 0.f, 0.f, 0.f, 0.f};
    for (int k = 0; k < 64; ++k) {
        const float wv = wfcp[n * 64 + k];
        #pragma unroll
        for (int m = 0; m < 8; ++m) {
            const int idx = (mb + m) * PH + k;
            s[m] += (b2f(h1h[idx]) + b2f(h1o[idx])) * wv;
        }
    }
    #pragma unroll
    for (int m = 0; m < 8; ++m)
        out[(size_t)(b0 + mb + m) * 128 + n] = s[m] + bfcp[n];
}

extern "C" void kernel_launch(void* const* d_in, const int* in_sizes, int n_in,
                              void* d_out, int out_size, void* d_ws, size_t ws_size,
                              hipStream_t stream) {
    const float* x     = (const float*)d_in[0];
    const float* wih0  = (const float*)d_in[1];
    const float* whh0  = (const float*)d_in[2];
    const float* bih0  = (const float*)d_in[3];
    const float* bhh0  = (const float*)d_in[4];
    const float* wih1  = (const float*)d_in[5];
    const float* whh1  = (const float*)d_in[6];
    const float* bih1  = (const float*)d_in[7];
    const float* bhh1  = (const float*)d_in[8];
    const float* wfc   = (const float*)d_in[9];
    const float* bfc   = (const float*)d_in[10];
    float* out = (float*)d_out;

    const size_t xp_bytes = (size_t)1024 * 256 * 256 * sizeof(_Float16); // 134 MB
    if (ws_size >= xp_bytes) {
        _Float16* xp = (_Float16*)d_ws;
        proj0_kernel<<<512, 512, 0, stream>>>(x, wih0, bih0, bhh0, xp);
        rec_kernel<<<128, 512, 0, stream>>>(xp, whh0, wih1, whh1, bih1, bhh1,
                                            wfc, bfc, out);
    } else {
        const size_t lds_bytes = (16 * XPI + 8 * HSZ) * sizeof(unsigned short);
        mega_fb<<<64, 256, lds_bytes, stream>>>(x, wih0, whh0, bih0, bhh0,
                                                wih1, whh1, bih1, bhh1, wfc, bfc, out);
    }
}

// Round 9
// 418.618 us; speedup vs baseline: 1.6944x; 1.1933x over previous
//
#include <hip/hip_runtime.h>

#define T_SEQ 256
#define PH  72
#define HSZ 1152

typedef __bf16 bf16x8 __attribute__((ext_vector_type(8)));
typedef float f32x4 __attribute__((ext_vector_type(4)));
typedef _Float16 f16x8 __attribute__((ext_vector_type(8)));

__device__ __forceinline__ float b2f(unsigned short u) {
    union { unsigned int i; float f; } v; v.i = ((unsigned int)u) << 16; return v.f;
}
__device__ __forceinline__ unsigned short f2b(float f) {
    unsigned int x = __builtin_bit_cast(unsigned int, f);
    unsigned int r = (x + 0x7fffu + ((x >> 16) & 1u)) >> 16;
    return (unsigned short)r;
}
__device__ __forceinline__ float sigmoid_f(float x) {
    float e = __builtin_amdgcn_exp2f(-1.4426950408889634f * x);
    return __builtin_amdgcn_rcpf(1.0f + e);
}
__device__ __forceinline__ float tanh_f(float x) {
    float e = __builtin_amdgcn_exp2f(-2.8853900817779268f * x);
    return 2.0f * __builtin_amdgcn_rcpf(1.0f + e) - 1.0f;
}
__device__ __forceinline__ void load_frag16(const float* wp, int n, int K, int k0,
                                            f16x8& hi, f16x8& lo) {
    const float* wf = wp + (size_t)n * K + k0;
    #pragma unroll
    for (int j = 0; j < 8; ++j) {
        const float v = wf[j];
        const _Float16 h = (_Float16)v;
        hi[j] = h;
        lo[j] = (_Float16)(v - (float)h);
    }
}
__device__ __forceinline__ f16x8 load_frag16h(const float* wp, int n, int K, int k0) {
    const float* wf = wp + (size_t)n * K + k0;
    f16x8 h;
    #pragma unroll
    for (int j = 0; j < 8; ++j) h[j] = (_Float16)wf[j];
    return h;
}
__device__ __forceinline__ void load_frag32(const float* wp, int n, int K, int k0,
                                            bf16x8& hi, bf16x8& lo) {
    const float* wf = wp + (size_t)n * K + k0;
    #pragma unroll
    for (int j = 0; j < 8; ++j) {
        const float v = wf[j];
        const unsigned short h = f2b(v);
        hi[j] = __builtin_bit_cast(__bf16, h);
        lo[j] = __builtin_bit_cast(__bf16, f2b(v - b2f(h)));
    }
}
__device__ __forceinline__ void gload16(const void* g, void* l) {
    __builtin_amdgcn_global_load_lds(
        (const __attribute__((address_space(1))) unsigned int*)g,
        (__attribute__((address_space(3))) unsigned int*)l, 16, 0, 0);
}

#define MFMA(a, b, c)   __builtin_amdgcn_mfma_f32_16x16x32_bf16(a, b, c, 0, 0, 0)
#define MFMA16(a, b, c) __builtin_amdgcn_mfma_f32_16x16x32_f16(a, b, c, 0, 0, 0)

// ================= proj0 v3: single-staged x tile, wih0 fp16 single-plane =================
// 512 blocks (64 bb x 8 t-chunks of 32) x 512 thr, 1 block/CU (140 KB LDS).
// xp[bb][t] (4096 halves): gp*2048 + (wl*64+quad*16+l16)*8 + gg*4 + r.
#define XTD 136    // d-stride (halves)
#define XRW 4376   // row stride (32*136 + 24 pad; dword stride %32 = 12 -> spread banks)
__global__ __launch_bounds__(512, 2) void proj0_kernel(
    const float* __restrict__ x, const float* __restrict__ wih0,
    const float* __restrict__ bih0, const float* __restrict__ bhh0,
    _Float16* __restrict__ xp)
{
    __shared__ _Float16 xh[16 * XRW];   // 140,032 B
    const int bb  = blockIdx.x >> 3;
    const int tch = (blockIdx.x & 7) * 32;
    const int tid = threadIdx.x, lane = tid & 63, wv = tid >> 6;
    const int l16 = lane & 15, quad = lane >> 4, k0 = quad * 8;
    const int wl = wv >> 1, gp = wv & 1;

    f16x8 fwh[2][4];
    float gb[2];
    #pragma unroll
    for (int gg = 0; gg < 2; ++gg) {
        const int n = (gp * 2 + gg) * 64 + wl * 16 + l16;
        #pragma unroll
        for (int ks = 0; ks < 4; ++ks)
            fwh[gg][ks] = load_frag16h(wih0, n, 128, ks * 32 + k0);
        gb[gg] = bih0[n] + bhh0[n];
    }

    // stage 16 rows x 128 d x 32 t ONCE (x read exactly once per element)
    #pragma unroll 4
    for (int it = 0; it < 32; ++it) {
        const int e = it * 512 + tid;       // e = row*1024 + d*8 + tq
        const int tq = e & 7, d = (e >> 3) & 127, row = e >> 10;
        const float4 v = *(const float4*)(x +
            ((size_t)(bb * 16 + row) * 128 + d) * 256 + tch + tq * 4);
        const float vv[4] = {v.x, v.y, v.z, v.w};
        #pragma unroll
        for (int j = 0; j < 4; ++j)
            xh[row * XRW + (tq * 4 + j) * XTD + d] = (_Float16)vv[j];
    }
    __syncthreads();

    for (int t = 0; t < 32; ++t) {
        f16x8 a_h[4];
        #pragma unroll
        for (int ks = 0; ks < 4; ++ks)
            a_h[ks] = *(const f16x8*)&xh[l16 * XRW + t * XTD + ks * 32 + k0];
        f32x4 acc[2];
        #pragma unroll
        for (int gg = 0; gg < 2; ++gg)
            acc[gg] = (f32x4){gb[gg], gb[gg], gb[gg], gb[gg]};
        #pragma unroll
        for (int gg = 0; gg < 2; ++gg)
            #pragma unroll
            for (int ks = 0; ks < 4; ++ks)
                acc[gg] = MFMA16(a_h[ks], fwh[gg][ks], acc[gg]);
        f16x8 o0;
        #pragma unroll
        for (int gg = 0; gg < 2; ++gg)
            #pragma unroll
            for (int r = 0; r < 4; ++r)
                o0[gg * 4 + r] = (_Float16)acc[gg][r];
        *(f16x8*)(xp + (size_t)(bb * 256 + tch + t) * 4096 + gp * 2048
                  + (wl * 64 + quad * 16 + l16) * 8) = o0;
    }
}

// ================= rec v4: 256 blocks x 4 real rows x 512 thr =================
// Real rows at m = quad*4 (r=0 only): global row bb*16 + quad*4 + sub.
// Siblings (same bb) are 64 apart in blockIdx -> same XCD -> shared L2 for xp.
// L1 waves (w<4): layer1, wih1 single-plane + whh1 hi/lo (24 MFMA).
// L0 waves: layer0, whh0 hi/lo (16 MFMA) + xp staging. One barrier/step.
__global__ __launch_bounds__(512, 2) void rec_kernel(
    const _Float16* __restrict__ xp,
    const float* __restrict__ whh0, const float* __restrict__ wih1,
    const float* __restrict__ whh1, const float* __restrict__ bih1,
    const float* __restrict__ bhh1, const float* __restrict__ wfc,
    const float* __restrict__ bfc, float* __restrict__ out)
{
    __shared__ _Float16 xpl[8 * 4096];   // 64 KB: 8 t-slots (2 chunks x 4)
    __shared__ _Float16 h0[2 * HSZ], h1[2 * HSZ];
    const int tid = threadIdx.x, lane = tid & 63, w = tid >> 6;
    const int l16 = lane & 15, quad = lane >> 4, k0 = quad * 8;
    const int wl = w & 3;
    const bool is1 = (w < 4);
    const int bb  = blockIdx.x & 63;
    const int sub = blockIdx.x >> 6;

    const char* gxp = (const char*)(xp + (size_t)bb * 256 * 4096);  // 8192 B/t
    char* xplB = (char*)xpl;

    if (!is1) {   // stage chunks 0,1 (t=0..7): full 8 KB/t across 4 L0 waves
        #pragma unroll
        for (int t = 0; t < 8; ++t)
            #pragma unroll
            for (int c2 = 0; c2 < 2; ++c2)
                gload16(gxp + (size_t)t * 8192 + (wl * 2 + c2) * 1024 + lane * 16,
                        xplB + t * 8192 + (wl * 2 + c2) * 1024);
    }

    f16x8 fAh[4][2], fAl[4][2], fBh[4][2], fBl[4][2];
    float gb1[4] = {0.f, 0.f, 0.f, 0.f};
    #pragma unroll
    for (int g = 0; g < 4; ++g) {
        const int n = g * 64 + wl * 16 + l16;
        if (is1) {
            #pragma unroll
            for (int ks = 0; ks < 2; ++ks) {
                fAh[g][ks] = load_frag16h(wih1, n, 64, ks * 32 + k0);
                load_frag16(whh1, n, 64, ks * 32 + k0, fBh[g][ks], fBl[g][ks]);
            }
            gb1[g] = bih1[n] + bhh1[n];
        } else {
            #pragma unroll
            for (int ks = 0; ks < 2; ++ks)
                load_frag16(whh0, n, 64, ks * 32 + k0, fAh[g][ks], fAl[g][ks]);
        }
    }
    for (int i = tid; i < 2 * HSZ; i += 512) { h0[i] = (_Float16)0.f; h1[i] = (_Float16)0.f; }
    float c = 0.f;   // the lane's single cell state (c1 for L1, c0 for L0)
    const int gbh = (wl * 64 + quad * 16 + l16) * 8;   // halves, within a t-slot

    __syncthreads();   // gloads drained (chunks 0,1 resident); h zeroed

    if (!is1) {        // prologue: layer0[0] (h0_init=0) -> h0 slot 0
        const float xi = (float)xpl[gbh + sub];
        const float xg = (float)xpl[2048 + gbh + sub];
        const float xo = (float)xpl[2048 + gbh + 4 + sub];
        const float gi = sigmoid_f(xi);
        const float gg = tanh_f(xg);
        const float go = sigmoid_f(xo);
        c = gi * gg;
        h0[(quad * 4) * PH + wl * 16 + l16] = (_Float16)(go * tanh_f(c));
    }
    __syncthreads();

    for (int t = 0; t < 255; ++t) {
        const int s0 = t & 1, s1 = s0 ^ 1;
        const int tn = t + 1;
        if (is1) {
            f16x8 ah[2], bh[2];
            #pragma unroll
            for (int ks = 0; ks < 2; ++ks) {
                ah[ks] = *(const f16x8*)&h0[s0 * HSZ + l16 * PH + ks * 32 + k0];
                bh[ks] = *(const f16x8*)&h1[s1 * HSZ + l16 * PH + ks * 32 + k0];
            }
            f32x4 acc[4];
            #pragma unroll
            for (int g = 0; g < 4; ++g)
                acc[g] = (f32x4){gb1[g], 0.f, 0.f, 0.f};
            #pragma unroll
            for (int g = 0; g < 4; ++g)
                #pragma unroll
                for (int ks = 0; ks < 2; ++ks) {
                    acc[g] = MFMA16(ah[ks], fAh[g][ks], acc[g]);
                    acc[g] = MFMA16(bh[ks], fBh[g][ks], acc[g]);
                    acc[g] = MFMA16(bh[ks], fBl[g][ks], acc[g]);
                }
            const float gi = sigmoid_f(acc[0][0]);
            const float gf = sigmoid_f(acc[1][0]);
            const float gg = tanh_f(acc[2][0]);
            const float go = sigmoid_f(acc[3][0]);
            c = gf * c + gi * gg;
            h1[s0 * HSZ + (quad * 4) * PH + wl * 16 + l16] =
                (_Float16)(go * tanh_f(c));
        } else {
            if ((tn & 3) == 0) {               // prefetch next 4-step chunk
                const int cc = (tn >> 2) + 1;
                if (cc < 64) {
                    #pragma unroll
                    for (int t2 = 0; t2 < 4; ++t2)
                        #pragma unroll
                        for (int c2 = 0; c2 < 2; ++c2)
                            gload16(gxp + (size_t)(cc * 4 + t2) * 8192
                                        + (wl * 2 + c2) * 1024 + lane * 16,
                                    xplB + ((cc & 1) * 4 + t2) * 8192
                                        + (wl * 2 + c2) * 1024);
                }
            }
            const int sb = (((tn >> 2) & 1) * 4 + (tn & 3)) * 4096 + gbh;
            const float xi = (float)xpl[sb + sub];
            const float xf = (float)xpl[sb + 4 + sub];
            const float xg = (float)xpl[sb + 2048 + sub];
            const float xo = (float)xpl[sb + 2048 + 4 + sub];
            f16x8 ah[2];
            #pragma unroll
            for (int ks = 0; ks < 2; ++ks)
                ah[ks] = *(const f16x8*)&h0[s0 * HSZ + l16 * PH + ks * 32 + k0];
            f32x4 acc[4];
            acc[0] = (f32x4){xi, 0.f, 0.f, 0.f};
            acc[1] = (f32x4){xf, 0.f, 0.f, 0.f};
            acc[2] = (f32x4){xg, 0.f, 0.f, 0.f};
            acc[3] = (f32x4){xo, 0.f, 0.f, 0.f};
            #pragma unroll
            for (int g = 0; g < 4; ++g)
                #pragma unroll
                for (int ks = 0; ks < 2; ++ks) {
                    acc[g] = MFMA16(ah[ks], fAh[g][ks], acc[g]);
                    acc[g] = MFMA16(ah[ks], fAl[g][ks], acc[g]);
                }
            const float gi = sigmoid_f(acc[0][0]);
            const float gf = sigmoid_f(acc[1][0]);
            const float gg = tanh_f(acc[2][0]);
            const float go = sigmoid_f(acc[3][0]);
            c = gf * c + gi * gg;
            h0[s1 * HSZ + (quad * 4) * PH + wl * 16 + l16] =
                (_Float16)(go * tanh_f(c));
        }
        __syncthreads();
    }

    if (is1) {   // epilogue: layer1[255] (h0 slot1, h1 slot0 -> h1 slot1)
        f16x8 ah[2], bh[2];
        #pragma unroll
        for (int ks = 0; ks < 2; ++ks) {
            ah[ks] = *(const f16x8*)&h0[HSZ + l16 * PH + ks * 32 + k0];
            bh[ks] = *(const f16x8*)&h1[l16 * PH + ks * 32 + k0];
        }
        f32x4 acc[4];
        #pragma unroll
        for (int g = 0; g < 4; ++g)
            acc[g] = (f32x4){gb1[g], 0.f, 0.f, 0.f};
        #pragma unroll
        for (int g = 0; g < 4; ++g)
            #pragma unroll
            for (int ks = 0; ks < 2; ++ks) {
                acc[g] = MFMA16(ah[ks], fAh[g][ks], acc[g]);
                acc[g] = MFMA16(bh[ks], fBh[g][ks], acc[g]);
                acc[g] = MFMA16(bh[ks], fBl[g][ks], acc[g]);
            }
        const float gi = sigmoid_f(acc[0][0]);
        const float gf = sigmoid_f(acc[1][0]);
        const float gg = tanh_f(acc[2][0]);
        const float go = sigmoid_f(acc[3][0]);
        c = gf * c + gi * gg;
        h1[HSZ + (quad * 4) * PH + wl * 16 + l16] = (_Float16)(go * tanh_f(c));
    }
    __syncthreads();

    // head: row m = sel*4 (slot 1); out row = bb*16 + sel*4 + sub
    const int n   = tid & 127;
    const int sel = tid >> 7;
    float s = 0.f;
    for (int k = 0; k < 64; ++k)
        s += (float)h1[HSZ + (sel * 4) * PH + k] * wfc[n * 64 + k];
    out[(size_t)(bb * 16 + sel * 4 + sub) * 128 + n] = s + bfc[n];
}

// ================= fallback: R4's proven fused kernel (small-ws path) =================
#define XPT 136
#define XPI 4360
__global__ __launch_bounds__(256, 1) void mega_fb(
    const float* __restrict__ x,
    const float* wih0p, const float* whh0p, const float* bih0p, const float* bhh0p,
    const float* wih1p, const float* whh1p, const float* bih1p, const float* bhh1p,
    const float* wfcp, const float* bfcp, float* out)
{
    extern __shared__ __align__(16) unsigned short smem[];
    unsigned short* xs  = smem;
    unsigned short* h0h = smem + 16 * XPI;
    unsigned short* h0o = h0h + 2 * HSZ;
    unsigned short* h1h = h0h + 4 * HSZ;
    unsigned short* h1o = h0h + 6 * HSZ;

    const int tid = threadIdx.x, lane = tid & 63, w = tid >> 6;
    const int l16 = lane & 15, quad = lane >> 4;
    const int b0 = blockIdx.x * 16, k0 = quad * 8;

    bf16x8 fih0h[4][4], fih0l[4][4], fhh0h[4][2], fhh0l[4][2];
    bf16x8 fih1h[4][2], fih1l[4][2], fhh1h[4][2], fhh1l[4][2];
    float gb0r[4], gb1r[4];
    #pragma unroll
    for (int g = 0; g < 4; ++g) {
        const int n = g * 64 + w * 16 + l16;
        #pragma unroll
        for (int ks = 0; ks < 4; ++ks)
            load_frag32(wih0p, n, 128, ks * 32 + k0, fih0h[g][ks], fih0l[g][ks]);
        #pragma unroll
        for (int ks = 0; ks < 2; ++ks) {
            load_frag32(whh0p, n, 64, ks * 32 + k0, fhh0h[g][ks], fhh0l[g][ks]);
            load_frag32(wih1p, n, 64, ks * 32 + k0, fih1h[g][ks], fih1l[g][ks]);
            load_frag32(whh1p, n, 64, ks * 32 + k0, fhh1h[g][ks], fhh1l[g][ks]);
        }
        gb0r[g] = bih0p[n] + bhh0p[n];
        gb1r[g] = bih1p[n] + bhh1p[n];
    }
    for (int i = tid; i < 8 * HSZ; i += 256) h0h[i] = 0;
    float c0[4] = {0.f, 0.f, 0.f, 0.f}, c1[4] = {0.f, 0.f, 0.f, 0.f};

    for (int tc = 0; tc < 16; ++tc) {
        __syncthreads();
        for (int l = 0; l < 32; ++l) {
            const int e = l * 256 + tid;
            const int cc = e & 3, d = (e >> 2) & 127, i = e >> 9;
            const float4 v = *(const float4*)(x +
                (((size_t)(b0 + i) * 128 + d) * 256 + tc * 16 + cc * 4));
            const float vv[4] = {v.x, v.y, v.z, v.w};
            #pragma unroll
            for (int j = 0; j < 4; ++j) {
                const unsigned short hi = f2b(vv[j]);
                xs[i * XPI + (cc * 4 + j) * XPT + d] = hi;
                xs[i * XPI + 2176 + (cc * 4 + j) * XPT + d] = f2b(vv[j] - b2f(hi));
            }
        }
        __syncthreads();
        for (int tt = 0; tt < 16; ++tt) {
            const int t = tc * 16 + tt;
            const int p = t & 1, q = p ^ 1;
            bf16x8 xa[4], xo[4], hh[2], ho[2];
            #pragma unroll
            for (int ks = 0; ks < 4; ++ks) {
                xa[ks] = *(const bf16x8*)&xs[l16 * XPI + tt * XPT + ks * 32 + k0];
                xo[ks] = *(const bf16x8*)&xs[l16 * XPI + 2176 + tt * XPT + ks * 32 + k0];
            }
            #pragma unroll
            for (int ks = 0; ks < 2; ++ks) {
                hh[ks] = *(const bf16x8*)&h0h[p * HSZ + l16 * PH + ks * 32 + k0];
                ho[ks] = *(const bf16x8*)&h0o[p * HSZ + l16 * PH + ks * 32 + k0];
            }
            f32x4 acc[4];
            #pragma unroll
            for (int g = 0; g < 4; ++g)
                acc[g] = (f32x4){gb0r[g], gb0r[g], gb0r[g], gb0r[g]};
            #pragma unroll
            for (int g = 0; g < 4; ++g) {
                #pragma unroll
                for (int ks = 0; ks < 4; ++ks) {
                    acc[g] = MFMA(xa[ks], fih0h[g][ks], acc[g]);
                    acc[g] = MFMA(xa[ks], fih0l[g][ks], acc[g]);
                    acc[g] = MFMA(xo[ks], fih0h[g][ks], acc[g]);
                }
                #pragma unroll
                for (int ks = 0; ks < 2; ++ks) {
                    acc[g] = MFMA(hh[ks], fhh0h[g][ks], acc[g]);
                    acc[g] = MFMA(ho[ks], fhh0h[g][ks], acc[g]);
                    acc[g] = MFMA(hh[ks], fhh0l[g][ks], acc[g]);
                }
            }
            #pragma unroll
            for (int r = 0; r < 4; ++r) {
                const float gi = sigmoid_f(acc[0][r]);
                const float gf = sigmoid_f(acc[1][r]);
                const float gg = tanh_f(acc[2][r]);
                const float go = sigmoid_f(acc[3][r]);
                c0[r] = gf * c0[r] + gi * gg;
                const float hv = go * tanh_f(c0[r]);
                const unsigned short hb = f2b(hv);
                const int idx = q * HSZ + (quad * 4 + r) * PH + w * 16 + l16;
                h0h[idx] = hb; h0o[idx] = f2b(hv - b2f(hb));
            }
            __syncthreads();
            bf16x8 ah[2], ao[2], bh[2], bo[2];
            #pragma unroll
            for (int ks = 0; ks < 2; ++ks) {
                ah[ks] = *(const bf16x8*)&h0h[q * HSZ + l16 * PH + ks * 32 + k0];
                ao[ks] = *(const bf16x8*)&h0o[q * HSZ + l16 * PH + ks * 32 + k0];
                bh[ks] = *(const bf16x8*)&h1h[p * HSZ + l16 * PH + ks * 32 + k0];
                bo[ks] = *(const bf16x8*)&h1o[p * HSZ + l16 * PH + ks * 32 + k0];
            }
            #pragma unroll
            for (int g = 0; g < 4; ++g)
                acc[g] = (f32x4){gb1r[g], gb1r[g], gb1r[g], gb1r[g]};
            #pragma unroll
            for (int g = 0; g < 4; ++g)
                #pragma unroll
                for (int ks = 0; ks < 2; ++ks) {
                    acc[g] = MFMA(ah[ks], fih1h[g][ks], acc[g]);
                    acc[g] = MFMA(ao[ks], fih1h[g][ks], acc[g]);
                    acc[g] = MFMA(bh[ks], fhh1h[g][ks], acc[g]);
                    acc[g] = MFMA(bo[ks], fhh1h[g][ks], acc[g]);
                    acc[g] = MFMA(ah[ks], fih1l[g][ks], acc[g]);
                    acc[g] = MFMA(bh[ks], fhh1l[g][ks], acc[g]);
                }
            #pragma unroll
            for (int r = 0; r < 4; ++r) {
                const float gi = sigmoid_f(acc[0][r]);
                const float gf = sigmoid_f(acc[1][r]);
                const float gg = tanh_f(acc[2][r]);
                const float go = sigmoid_f(acc[3][r]);
                c1[r] = gf * c1[r] + gi * gg;
                const float hv = go * tanh_f(c1[r]);
                const unsigned short hb = f2b(hv);
                const int idx = q * HSZ + (quad * 4 + r) * PH + w * 16 + l16;
                h1h[idx] = hb; h1o[idx] = f2b(hv - b2f(hb));
            }
            __syncthreads();
        }
    }
    const int n = tid & 127;
    const int mb = (tid >> 7) * 8;
    float s[8] = {0.f, 0.f, 0.f, 0.f, 0.f, 0.f, 0.f, 0.f};
    for (int k = 0; k < 64; ++k) {
        const float wv = wfcp[n * 64 + k];
        #pragma unroll
        for (int m = 0; m < 8; ++m) {
            const int idx = (mb + m) * PH + k;
            s[m] += (b2f(h1h[idx]) + b2f(h1o[idx])) * wv;
        }
    }
    #pragma unroll
    for (int m = 0; m < 8; ++m)
        out[(size_t)(b0 + mb + m) * 128 + n] = s[m] + bfcp[n];
}

extern "C" void kernel_launch(void* const* d_in, const int* in_sizes, int n_in,
                              void* d_out, int out_size, void* d_ws, size_t ws_size,
                              hipStream_t stream) {
    const float* x     = (const float*)d_in[0];
    const float* wih0  = (const float*)d_in[1];
    const float* whh0  = (const float*)d_in[2];
    const float* bih0  = (const float*)d_in[3];
    const float* bhh0  = (const float*)d_in[4];
    const float* wih1  = (const float*)d_in[5];
    const float* whh1  = (const float*)d_in[6];
    const float* bih1  = (const float*)d_in[7];
    const float* bhh1  = (const float*)d_in[8];
    const float* wfc   = (const float*)d_in[9];
    const float* bfc   = (const float*)d_in[10];
    float* out = (float*)d_out;

    const size_t xp_bytes = (size_t)1024 * 256 * 256 * sizeof(_Float16); // 134 MB
    if (ws_size >= xp_bytes) {
        _Float16* xp = (_Float16*)d_ws;
        proj0_kernel<<<512, 512, 0, stream>>>(x, wih0, bih0, bhh0, xp);
        rec_kernel<<<256, 512, 0, stream>>>(xp, whh0, wih1, whh1, bih1, bhh1,
                                            wfc, bfc, out);
    } else {
        const size_t lds_bytes = (16 * XPI + 8 * HSZ) * sizeof(unsigned short);
        mega_fb<<<64, 256, lds_bytes, stream>>>(x, wih0, whh0, bih0, bhh0,
                                                wih1, whh1, bih1, bhh1, wfc, bfc, out);
    }
}